// Round 13
// baseline (375.841 us; speedup 1.0000x reference)
//
#include <hip/hip_runtime.h>
#include <utility>

#define DIM 2048
#define NQ 11
#define NROT 88
#define BSZ 64
#define NT 8
#define NPC 4   // DEGREE+1

#if __has_builtin(__builtin_amdgcn_permlane16_swap)
#define HAVE_PL16 1
#else
#define HAVE_PL16 0
#endif
#if __has_builtin(__builtin_amdgcn_permlane32_swap)
#define HAVE_PL32 1
#else
#define HAVE_PL32 0
#endif

// ---------------------------------------------------------------------------
// Compile-time gate schedule. Gate G in [0,88); wire w <-> state bit 10-w.
// ---------------------------------------------------------------------------
constexpr int g_type(int G) {
    int j = G % 44;
    return (j < 11 || (j >= 22 && j < 33)) ? 0 : 1;   // 0=RY, 1=CRX
}
constexpr int g_pt(int G) {
    int j = G % 44;
    if (j < 11) return 10 - j;
    if (j < 22) { int i = 21 - j; int tw = (i + 1 == NQ) ? 0 : i + 1; return 10 - tw; }
    if (j < 33) return 10 - (j - 22);
    if (j == 33) return 1;
    int i = j - 34; int tw = (i + 10) % NQ; return 10 - tw;
}
constexpr int g_pcb(int G) {
    int j = G % 44;
    if (j >= 11 && j < 22) { int i = 21 - j; return 10 - i; }
    if (j == 33) return 0;
    if (j >= 34) { int i = j - 34; return 10 - i; }
    return -1;  // RY
}
constexpr bool use_sum_tier(int lb) {
    return (lb == 4 && HAVE_PL16) || (lb == 5 && HAVE_PL32);
}

// Transposed-layout bit map: swap state bits 2<->8, 3<->9, 5<->10 (r9-proven).
constexpr int tmap(int b) {
    if (b == 2) return 8;  if (b == 8) return 2;
    if (b == 3) return 9;  if (b == 9) return 3;
    if (b == 5) return 10; if (b == 10) return 5;
    return b;
}

// ---------------------------------------------------------------------------
// Per-layer op schedule (48 ops: 44 gates + 4 transposes), r9-proven.
// ---------------------------------------------------------------------------
constexpr int lop_j(int k) {
    if (k < 8)  return 3 + k;
    if (k == 8) return -1;
    if (k < 12) return k - 9;
    if (k == 12) return 11;
    if (k == 13) return -1;
    if (k < 22) return 12 + (k - 14);
    if (k == 22) return -1;
    if (k == 23) return 20;
    if (k == 24) return 21;
    if (k < 31) { int w[6] = {0, 1, 2, 3, 9, 10}; return 22 + w[k - 25]; }
    if (k < 36) return 33 + (k - 31);
    if (k == 36) return -1;
    if (k < 42) return 26 + (k - 37);
    return 38 + (k - 42);
}
constexpr bool lop_B(int k) {
    return (k >= 9 && k <= 12) || (k >= 23 && k <= 35);
}
constexpr int lop_tpar(int k) { return (k == 8 || k == 22) ? 0 : 1; }

// ---------------------------------------------------------------------------
// Wave-uniform trig fetch via readlane.
// ---------------------------------------------------------------------------
template<int G>
__device__ __forceinline__ void get_cs(float c0, float s0, float c1, float s1,
                                       float& c, float& s) {
    if constexpr (G < 64) {
        c = __int_as_float(__builtin_amdgcn_readlane(__float_as_int(c0), G));
        s = __int_as_float(__builtin_amdgcn_readlane(__float_as_int(s0), G));
    } else {
        c = __int_as_float(__builtin_amdgcn_readlane(__float_as_int(c1), G - 64));
        s = __int_as_float(__builtin_amdgcn_readlane(__float_as_int(s1), G - 64));
    }
}

// ---------------------------------------------------------------------------
// Lane exchange across tid bit LB (state bit LB+2) — PARTNER form.
// ---------------------------------------------------------------------------
template<int LB>
__device__ __forceinline__ float lxp(float x) {
    if constexpr (LB == 0) {
        return __int_as_float(__builtin_amdgcn_update_dpp(
            __float_as_int(x), __float_as_int(x), 0xB1, 0xF, 0xF, true)); // xor1
    } else if constexpr (LB == 1) {
        return __int_as_float(__builtin_amdgcn_update_dpp(
            __float_as_int(x), __float_as_int(x), 0x4E, 0xF, 0xF, true)); // xor2
    } else if constexpr (LB == 2) {
        return __int_as_float(__builtin_amdgcn_ds_swizzle(__float_as_int(x), 0x101F)); // xor4
    } else if constexpr (LB == 3) {
        return __int_as_float(__builtin_amdgcn_update_dpp(
            __float_as_int(x), __float_as_int(x), 0x128, 0xF, 0xF, true)); // row_ror:8 = xor8
    } else if constexpr (LB == 4) {
        return __int_as_float(__builtin_amdgcn_ds_swizzle(__float_as_int(x), 0x401F)); // xor16
    } else {
        return __shfl_xor(x, 32, 64);                                                  // xor32
    }
}

// SUM form: returns own + partner (order-immune to permlane*_swap ordering).
template<int LB>
__device__ __forceinline__ float lxsum(float x) {
#if HAVE_PL16
    if constexpr (LB == 4) {
        unsigned u = __float_as_uint(x);
        auto r = __builtin_amdgcn_permlane16_swap(u, u, false, false);
        return __uint_as_float(r[0]) + __uint_as_float(r[1]);
    }
#endif
#if HAVE_PL32
    if constexpr (LB == 5) {
        unsigned u = __float_as_uint(x);
        auto r = __builtin_amdgcn_permlane32_swap(u, u, false, false);
        return __uint_as_float(r[0]) + __uint_as_float(r[1]);
    }
#endif
    return x + lxp<LB>(x);
}

// ---------------------------------------------------------------------------
// Layout: 512 threads, thread tid holds amps a = tid*4 + (2m+e), m,e in {0,1}.
//   amp bits: 0=e, 1=m, 2..7=lane(tid 0..5), 8..10=block(tid 6..8)
// Layout B via transpose: bits (2,3,5) <-> (8,9,10).  [r9-proven, 85.2us]
// ---------------------------------------------------------------------------
template<int G, bool PB>
__device__ __forceinline__ void apply_gate(
    float2 (&R)[2], float2 (&I)[2],
    float c0, float s0, float c1, float s1, const int tid)
{
    constexpr int type = g_type(G);
    constexpr int pt   = PB ? tmap(g_pt(G)) : g_pt(G);
    constexpr int pcb0 = g_pcb(G);
    constexpr int pcb  = (pcb0 < 0) ? -1 : (PB ? tmap(pcb0) : pcb0);
    static_assert(pt <= 7, "block-bit target must run in transposed layout");
    float c, s;
    get_cs<G>(c0, s0, c1, s1, c, s);

    if constexpr (pt == 0) {
        if constexpr (type == 0) {
#pragma unroll
            for (int m = 0; m < 2; ++m) {
                float er = R[m].x, orr = R[m].y, ei = I[m].x, oi = I[m].y;
                R[m].x = c*er - s*orr;  R[m].y = s*er + c*orr;
                I[m].x = c*ei - s*oi;   I[m].y = s*ei + c*oi;
            }
        } else if constexpr (pcb == 1) {
            float er = R[1].x, orr = R[1].y, ei = I[1].x, oi = I[1].y;
            R[1].x = c*er + s*oi;   I[1].x = c*ei - s*orr;
            R[1].y = c*orr + s*ei;  I[1].y = c*oi - s*er;
        } else {
            const bool ctrl = (tid >> (pcb - 2)) & 1;
            if (ctrl) {
#pragma unroll
                for (int m = 0; m < 2; ++m) {
                    float er = R[m].x, orr = R[m].y, ei = I[m].x, oi = I[m].y;
                    R[m].x = c*er + s*oi;   I[m].x = c*ei - s*orr;
                    R[m].y = c*orr + s*ei;  I[m].y = c*oi - s*er;
                }
            }
        }
    } else if constexpr (pt == 1) {
        if constexpr (type == 0) {
            float2 l = R[0], h = R[1], li = I[0], hi = I[1];
            R[0].x = c*l.x - s*h.x;   R[0].y = c*l.y - s*h.y;
            R[1].x = s*l.x + c*h.x;   R[1].y = s*l.y + c*h.y;
            I[0].x = c*li.x - s*hi.x; I[0].y = c*li.y - s*hi.y;
            I[1].x = s*li.x + c*hi.x; I[1].y = s*li.y + c*hi.y;
        } else if constexpr (pcb == 0) {
            float lr = R[0].y, li = I[0].y, hr = R[1].y, hi = I[1].y;
            R[0].y = c*lr + s*hi;   I[0].y = c*li - s*hr;
            R[1].y = c*hr + s*li;   I[1].y = c*hi - s*lr;
        } else {
            const bool ctrl = (tid >> (pcb - 2)) & 1;
            if (ctrl) {
                float2 l = R[0], h = R[1], li = I[0], hi = I[1];
                R[0].x = c*l.x + s*hi.x;  R[0].y = c*l.y + s*hi.y;
                I[0].x = c*li.x - s*h.x;  I[0].y = c*li.y - s*h.y;
                R[1].x = c*h.x + s*li.x;  R[1].y = c*h.y + s*li.y;
                I[1].x = c*hi.x - s*l.x;  I[1].y = c*hi.y - s*l.y;
            }
        }
    } else {
        constexpr int lb = pt - 2;
        if constexpr (use_sum_tier(lb)) {
            if constexpr (type == 0) {
                const float sg = ((tid >> lb) & 1) ? s : -s;
                const float k1 = c - sg;
#pragma unroll
                for (int m = 0; m < 2; ++m) {
                    float srx = lxsum<lb>(R[m].x), sry = lxsum<lb>(R[m].y);
                    float six = lxsum<lb>(I[m].x), siy = lxsum<lb>(I[m].y);
                    R[m].x = k1*R[m].x + sg*srx;  R[m].y = k1*R[m].y + sg*sry;
                    I[m].x = k1*I[m].x + sg*six;  I[m].y = k1*I[m].y + sg*siy;
                }
            } else if constexpr (pcb == 0) {
#pragma unroll
                for (int m = 0; m < 2; ++m) {
                    float sR = lxsum<lb>(R[m].y), sI = lxsum<lb>(I[m].y);
                    float r = R[m].y, i = I[m].y;
                    R[m].y = c*r - s*i + s*sI;
                    I[m].y = c*i + s*r - s*sR;
                }
            } else if constexpr (pcb == 1) {
                float sRx = lxsum<lb>(R[1].x), sRy = lxsum<lb>(R[1].y);
                float sIx = lxsum<lb>(I[1].x), sIy = lxsum<lb>(I[1].y);
                float rx = R[1].x, ry = R[1].y, ix = I[1].x, iy = I[1].y;
                R[1].x = c*rx - s*ix + s*sIx;  R[1].y = c*ry - s*iy + s*sIy;
                I[1].x = c*ix + s*rx - s*sRx;  I[1].y = c*iy + s*ry - s*sRy;
            } else {
                const bool ctrl = (tid >> (pcb - 2)) & 1;
                if (ctrl) {
#pragma unroll
                    for (int m = 0; m < 2; ++m) {
                        float sRx = lxsum<lb>(R[m].x), sRy = lxsum<lb>(R[m].y);
                        float sIx = lxsum<lb>(I[m].x), sIy = lxsum<lb>(I[m].y);
                        float rx = R[m].x, ry = R[m].y, ix = I[m].x, iy = I[m].y;
                        R[m].x = c*rx - s*ix + s*sIx;  R[m].y = c*ry - s*iy + s*sIy;
                        I[m].x = c*ix + s*rx - s*sRx;  I[m].y = c*iy + s*ry - s*sRy;
                    }
                }
            }
        } else {
            if constexpr (type == 0) {
                const float sg = ((tid >> lb) & 1) ? s : -s;
#pragma unroll
                for (int m = 0; m < 2; ++m) {
                    float prx = lxp<lb>(R[m].x), pry = lxp<lb>(R[m].y);
                    float pix = lxp<lb>(I[m].x), piy = lxp<lb>(I[m].y);
                    R[m].x = c*R[m].x + sg*prx;  R[m].y = c*R[m].y + sg*pry;
                    I[m].x = c*I[m].x + sg*pix;  I[m].y = c*I[m].y + sg*piy;
                }
            } else if constexpr (pcb == 0) {
#pragma unroll
                for (int m = 0; m < 2; ++m) {
                    float pry = lxp<lb>(R[m].y), piy = lxp<lb>(I[m].y);
                    R[m].y = c*R[m].y + s*piy;
                    I[m].y = c*I[m].y - s*pry;
                }
            } else if constexpr (pcb == 1) {
                float prx = lxp<lb>(R[1].x), pry = lxp<lb>(R[1].y);
                float pix = lxp<lb>(I[1].x), piy = lxp<lb>(I[1].y);
                R[1].x = c*R[1].x + s*pix;  R[1].y = c*R[1].y + s*piy;
                I[1].x = c*I[1].x - s*prx;  I[1].y = c*I[1].y - s*pry;
            } else {
                const bool ctrl = (tid >> (pcb - 2)) & 1;
                if (ctrl) {
#pragma unroll
                    for (int m = 0; m < 2; ++m) {
                        float prx = lxp<lb>(R[m].x), pry = lxp<lb>(R[m].y);
                        float pix = lxp<lb>(I[m].x), piy = lxp<lb>(I[m].y);
                        R[m].x = c*R[m].x + s*pix;  R[m].y = c*R[m].y + s*piy;
                        I[m].x = c*I[m].x - s*prx;  I[m].y = c*I[m].y - s*pry;
                    }
                }
            }
        }
    }
}

// ---------------------------------------------------------------------------
// Whole-payload thread transpose: swap tid bits (0,1,3) <-> (6,7,8) via LDS.
// ---------------------------------------------------------------------------
__device__ __forceinline__ int swz(int s) { return s ^ ((s >> 7) & 7); }

template<int PAR>
__device__ __forceinline__ void transpose_swap(float2 (&R)[2], float2 (&I)[2],
                                               float4* __restrict__ exbuf, const int tid)
{
    float4* buf = exbuf + PAR * 1024;
    const int d06 = ((tid >> 0) ^ (tid >> 6)) & 1;
    const int d17 = ((tid >> 1) ^ (tid >> 7)) & 1;
    const int d38 = ((tid >> 3) ^ (tid >> 8)) & 1;
    const int q = tid ^ (d06 * 65) ^ (d17 * 130) ^ (d38 * 264);
    buf[swz(tid * 2 + 0)] = make_float4(R[0].x, R[0].y, I[0].x, I[0].y);
    buf[swz(tid * 2 + 1)] = make_float4(R[1].x, R[1].y, I[1].x, I[1].y);
    __syncthreads();
    float4 v0 = buf[swz(q * 2 + 0)];
    float4 v1 = buf[swz(q * 2 + 1)];
    R[0] = make_float2(v0.x, v0.y); I[0] = make_float2(v0.z, v0.w);
    R[1] = make_float2(v1.x, v1.y); I[1] = make_float2(v1.z, v1.w);
    // no trailing barrier: parity buffer reused 2 transposes later; the
    // intervening transpose's barrier orders those reads before writes.
}

// ---------------------------------------------------------------------------
// Op dispatcher over the 96-op schedule (2 layers x 48).
// ---------------------------------------------------------------------------
template<int K>
__device__ __forceinline__ void apply_op(
    float2 (&R)[2], float2 (&I)[2],
    float c0, float s0, float c1, float s1,
    float4* __restrict__ exbuf, const int tid)
{
    constexpr int layer = K / 48;
    constexpr int k = K % 48;
    constexpr int j = lop_j(k);
    if constexpr (j < 0) {
        transpose_swap<lop_tpar(k)>(R, I, exbuf, tid);
    } else {
        apply_gate<layer * 44 + j, lop_B(k)>(R, I, c0, s0, c1, s1, tid);
    }
}

template<int... Ks>
__device__ __forceinline__ void apply_all(std::integer_sequence<int, Ks...>,
    float2 (&R)[2], float2 (&I)[2],
    float c0, float s0, float c1, float s1,
    float4* __restrict__ exbuf, const int tid)
{
    (apply_op<Ks>(R, I, c0, s0, c1, s1, exbuf, tid), ...);
}

__device__ __forceinline__ void evolve_once(float2 (&R)[2], float2 (&I)[2],
    float c0, float s0, float c1, float s1,
    float4* __restrict__ exbuf, const int tid)
{
    apply_all(std::make_integer_sequence<int, 96>{}, R, I, c0, s0, c1, s1, exbuf, tid);
}

// ---------------------------------------------------------------------------
// Mono kernel: all 3 polynomial steps + final in ONE launch.
// Per-b 8-block flag barrier (device-scope atomics), no grid.sync.
// Flags zeroed by hipMemsetAsync before each call -> replay-safe.
// __launch_bounds__(512,8) caps VGPR<=64 -> >=4 blocks/CU residency ->
// all 512 blocks co-resident (deadlock-proof even with a disabled CU).
// ---------------------------------------------------------------------------
__global__ __launch_bounds__(512, 8) void mono_kernel(
    const float* __restrict__ base, const float* __restrict__ uparams,
    const float* __restrict__ lcu, const float* __restrict__ pcoef,
    float2* __restrict__ acc, float2* __restrict__ pA,
    float2* __restrict__ pB, float2* __restrict__ pC,
    int* __restrict__ flags, float* __restrict__ out)
{
    __shared__ float4 exbuf[2048];          // 32 KB dbuf
    __shared__ float red[9];

    const int b = blockIdx.x >> 3;
    const int t = blockIdx.x & 7;
    const int tid = threadIdx.x;
    const int lane = tid & 63;
    int* fl = flags + b * 3 * 8;            // [k][t]

    // trig once, reused by all 3 steps
    const float* __restrict__ th_row = uparams + (size_t)(b * NT + t) * NROT;
    float th0 = 0.5f * th_row[lane];
    float th1 = (lane < NROT - 64) ? 0.5f * th_row[64 + lane] : 0.f;
    const float tc0 = cosf(th0), ts0 = sinf(th0);
    const float tc1 = cosf(th1), ts1 = sinf(th1);
    const float coeff = lcu[b * NT + t];

#define STEP_SYNC(K)                                                           \
    __syncthreads();                                                           \
    if (tid == 0)                                                              \
        __hip_atomic_store(&fl[(K)*8 + t], (K) + 1, __ATOMIC_RELEASE,          \
                           __HIP_MEMORY_SCOPE_AGENT);                          \
    if (tid < 8) {                                                             \
        while (__hip_atomic_load(&fl[(K)*8 + tid], __ATOMIC_RELAXED,           \
                                 __HIP_MEMORY_SCOPE_AGENT) != (K) + 1)         \
            __builtin_amdgcn_s_sleep(2);                                       \
    }                                                                          \
    __syncthreads();                                                           \
    __threadfence();

    float2 R[2], I[2];
    // ---- step 0: normalize base; t==0 writes acc = pc0*base
    {
        const float4* b4 = (const float4*)(base + (size_t)b * DIM);
        float4 v = b4[tid];
        float loc = v.x*v.x + v.y*v.y + v.z*v.z + v.w*v.w;
        for (int off = 32; off > 0; off >>= 1) loc += __shfl_down(loc, off, 64);
        if ((tid & 63) == 0) red[tid >> 6] = loc;
        __syncthreads();
        if (tid == 0) { float sm = 0.f; for (int w = 0; w < 8; ++w) sm += red[w]; red[8] = sm; }
        __syncthreads();
        const float inv = rsqrtf(red[8]);
        R[0] = make_float2(v.x * inv, v.y * inv);
        R[1] = make_float2(v.z * inv, v.w * inv);
        I[0] = make_float2(0.f, 0.f);
        I[1] = make_float2(0.f, 0.f);
        if (t == 0) {
            const float p0 = pcoef[0];
            float4* a4 = (float4*)(acc + (size_t)b * DIM);
            a4[tid*2+0] = make_float4(p0*R[0].x, 0.f, p0*R[0].y, 0.f);
            a4[tid*2+1] = make_float4(p0*R[1].x, 0.f, p0*R[1].y, 0.f);
        }
        __syncthreads();
    }
    evolve_once(R, I, tc0, ts0, tc1, ts1, exbuf, tid);
    {
        float4* o4 = (float4*)(pA + ((size_t)b * NT + t) * DIM);
#pragma unroll
        for (int m = 0; m < 2; ++m)
            o4[tid*2+m] = make_float4(coeff*R[m].x, coeff*I[m].x, coeff*R[m].y, coeff*I[m].y);
    }
    STEP_SYNC(0)

    // ---- step 1: reduce pA; t==0 folds pc1; evolve; write pB
    {
        R[0] = make_float2(0.f, 0.f); R[1] = make_float2(0.f, 0.f);
        I[0] = make_float2(0.f, 0.f); I[1] = make_float2(0.f, 0.f);
        for (int cc = 0; cc < NT; ++cc) {
            const float4* p4 = (const float4*)(pA + ((size_t)b * NT + cc) * DIM);
#pragma unroll
            for (int m = 0; m < 2; ++m) {
                float4 v = p4[tid*2+m];
                R[m].x += v.x; I[m].x += v.y; R[m].y += v.z; I[m].y += v.w;
            }
        }
        if (t == 0) {
            const float pk = pcoef[1];
            float4* a4 = (float4*)(acc + (size_t)b * DIM);
#pragma unroll
            for (int m = 0; m < 2; ++m) {
                float4 v = a4[tid*2+m];
                v.x += pk * R[m].x; v.y += pk * I[m].x;
                v.z += pk * R[m].y; v.w += pk * I[m].y;
                a4[tid*2+m] = v;
            }
        }
    }
    evolve_once(R, I, tc0, ts0, tc1, ts1, exbuf, tid);
    {
        float4* o4 = (float4*)(pB + ((size_t)b * NT + t) * DIM);
#pragma unroll
        for (int m = 0; m < 2; ++m)
            o4[tid*2+m] = make_float4(coeff*R[m].x, coeff*I[m].x, coeff*R[m].y, coeff*I[m].y);
    }
    STEP_SYNC(1)

    // ---- step 2: reduce pB; t==0 folds pc2; evolve; write pC
    {
        R[0] = make_float2(0.f, 0.f); R[1] = make_float2(0.f, 0.f);
        I[0] = make_float2(0.f, 0.f); I[1] = make_float2(0.f, 0.f);
        for (int cc = 0; cc < NT; ++cc) {
            const float4* p4 = (const float4*)(pB + ((size_t)b * NT + cc) * DIM);
#pragma unroll
            for (int m = 0; m < 2; ++m) {
                float4 v = p4[tid*2+m];
                R[m].x += v.x; I[m].x += v.y; R[m].y += v.z; I[m].y += v.w;
            }
        }
        if (t == 0) {
            const float pk = pcoef[2];
            float4* a4 = (float4*)(acc + (size_t)b * DIM);
#pragma unroll
            for (int m = 0; m < 2; ++m) {
                float4 v = a4[tid*2+m];
                v.x += pk * R[m].x; v.y += pk * I[m].x;
                v.z += pk * R[m].y; v.w += pk * I[m].y;
                a4[tid*2+m] = v;
            }
        }
    }
    evolve_once(R, I, tc0, ts0, tc1, ts1, exbuf, tid);
    {
        float4* o4 = (float4*)(pC + ((size_t)b * NT + t) * DIM);
#pragma unroll
        for (int m = 0; m < 2; ++m)
            o4[tid*2+m] = make_float4(coeff*R[m].x, coeff*I[m].x, coeff*R[m].y, coeff*I[m].y);
    }
    STEP_SYNC(2)

    // ---- final: block (b,t) writes its 256-complex slice
    if (tid < 256) {
        const int i = t * 256 + tid;
        float sr = 0.f, si = 0.f;
        for (int cc = 0; cc < NT; ++cc) {
            float2 v = pC[((size_t)b * NT + cc) * DIM + i];
            sr += v.x; si += v.y;
        }
        float sabs = 0.f;
        for (int q = 0; q < NPC; ++q) sabs += fabsf(pcoef[q]);
        const float invn = 1.0f / sabs;
        const float pk = pcoef[NPC - 1];
        float2 a = acc[(size_t)b * DIM + i];
        out[((size_t)b * DIM + i) * 2 + 0] = (a.x + pk * sr) * invn;
        out[((size_t)b * DIM + i) * 2 + 1] = (a.y + pk * si) * invn;
    }
#undef STEP_SYNC
}

// ---------------------------------------------------------------------------
// Fallback multi-launch kernels (r9-proven path, used if ws too small).
// ---------------------------------------------------------------------------
template<int MODE>
__global__ __launch_bounds__(512, 4) void evolve_kernel(
    const void* __restrict__ src, const float* __restrict__ uparams,
    const float* __restrict__ lcu, float2* __restrict__ pout,
    const float* __restrict__ pcoef, float2* __restrict__ acc, int kprev)
{
    __shared__ float4 exbuf[2048];
    __shared__ float red[9];

    const int b = blockIdx.x >> 3;
    const int t = blockIdx.x & 7;
    const int tid = threadIdx.x;
    const int lane = tid & 63;

    const float* __restrict__ th_row = uparams + (size_t)(b * NT + t) * NROT;
    float th0 = 0.5f * th_row[lane];
    float th1 = (lane < NROT - 64) ? 0.5f * th_row[64 + lane] : 0.f;
    float tc0 = cosf(th0), ts0 = sinf(th0);
    float tc1 = cosf(th1), ts1 = sinf(th1);

    float2 R[2], I[2];
    if constexpr (MODE == 0) {
        const float4* b4 = (const float4*)((const float*)src + (size_t)b * DIM);
        float4 v = b4[tid];
        float loc = v.x*v.x + v.y*v.y + v.z*v.z + v.w*v.w;
        for (int off = 32; off > 0; off >>= 1) loc += __shfl_down(loc, off, 64);
        if ((tid & 63) == 0) red[tid >> 6] = loc;
        __syncthreads();
        if (tid == 0) { float sm = 0.f; for (int w = 0; w < 8; ++w) sm += red[w]; red[8] = sm; }
        __syncthreads();
        const float inv = rsqrtf(red[8]);
        R[0] = make_float2(v.x * inv, v.y * inv);
        R[1] = make_float2(v.z * inv, v.w * inv);
        I[0] = make_float2(0.f, 0.f);
        I[1] = make_float2(0.f, 0.f);
        if (t == 0) {
            const float p0 = pcoef[0];
            float4* a4 = (float4*)(acc + (size_t)b * DIM);
            a4[tid*2+0] = make_float4(p0*R[0].x, 0.f, p0*R[0].y, 0.f);
            a4[tid*2+1] = make_float4(p0*R[1].x, 0.f, p0*R[1].y, 0.f);
        }
        __syncthreads();
    } else {
        R[0] = make_float2(0.f, 0.f); R[1] = make_float2(0.f, 0.f);
        I[0] = make_float2(0.f, 0.f); I[1] = make_float2(0.f, 0.f);
        const float2* s2 = (const float2*)src;
        for (int cc = 0; cc < NT; ++cc) {
            const float4* p4 = (const float4*)(s2 + ((size_t)b * NT + cc) * DIM);
#pragma unroll
            for (int m = 0; m < 2; ++m) {
                float4 v = p4[tid*2+m];
                R[m].x += v.x; I[m].x += v.y; R[m].y += v.z; I[m].y += v.w;
            }
        }
        if (t == 0 && kprev > 0) {
            const float pk = pcoef[kprev];
            float4* a4 = (float4*)(acc + (size_t)b * DIM);
#pragma unroll
            for (int m = 0; m < 2; ++m) {
                float4 v = a4[tid*2+m];
                v.x += pk * R[m].x; v.y += pk * I[m].x;
                v.z += pk * R[m].y; v.w += pk * I[m].y;
                a4[tid*2+m] = v;
            }
        }
    }

    evolve_once(R, I, tc0, ts0, tc1, ts1, exbuf, tid);

    const float coeff = lcu[b * NT + t];
    float4* o4 = (float4*)(pout + ((size_t)b * NT + t) * DIM);
#pragma unroll
    for (int m = 0; m < 2; ++m)
        o4[tid*2+m] = make_float4(coeff*R[m].x, coeff*I[m].x, coeff*R[m].y, coeff*I[m].y);
}

__global__ __launch_bounds__(256) void final_kernel(
    const float2* __restrict__ partial, const float* __restrict__ pcoef,
    const float2* __restrict__ acc, float* __restrict__ out)
{
    int b = blockIdx.x >> 3;
    int i = ((blockIdx.x & 7) << 8) | threadIdx.x;
    float sr = 0.f, si = 0.f;
    for (int c = 0; c < NT; ++c) {
        float2 v = partial[((size_t)b * NT + c) * DIM + i];
        sr += v.x; si += v.y;
    }
    float sabs = 0.f;
    for (int q = 0; q < NPC; ++q) sabs += fabsf(pcoef[q]);
    float invn = 1.0f / sabs;
    float pk = pcoef[NPC - 1];
    float2 a = acc[(size_t)b * DIM + i];
    out[((size_t)b * DIM + i) * 2 + 0] = (a.x + pk * sr) * invn;
    out[((size_t)b * DIM + i) * 2 + 1] = (a.y + pk * si) * invn;
}

extern "C" void kernel_launch(void* const* d_in, const int* in_sizes, int n_in,
                              void* d_out, int out_size, void* d_ws, size_t ws_size,
                              hipStream_t stream) {
    const float* base = (const float*)d_in[0];   // (64, 2048) f32
    const float* upar = (const float*)d_in[1];   // (64, 8, 88) f32
    const float* lcu  = (const float*)d_in[2];   // (64, 8) f32
    const float* pc   = (const float*)d_in[3];   // (4,) f32
    float* out = (float*)d_out;                  // (64, 2048, 2) f32

    const size_t plane = (size_t)BSZ * DIM * sizeof(float2);   // 1 MB
    const size_t flags_bytes = (size_t)BSZ * 3 * 8 * sizeof(int);
    char* ws = (char*)d_ws;

    float2* acc = (float2*)ws;
    float2* pA  = (float2*)(ws + plane);
    float2* pB  = (float2*)(ws + plane + (size_t)NT * plane);
    float2* pC  = (float2*)(ws + plane + (size_t)2 * NT * plane);
    int* flags  = (int*)(ws + (1 + 3 * (size_t)NT) * plane);

    if (ws_size >= (1 + 3 * (size_t)NT) * plane + flags_bytes) {
        hipMemsetAsync(flags, 0, flags_bytes, stream);
        mono_kernel<<<BSZ * NT, 512, 0, stream>>>(base, upar, lcu, pc,
                                                  acc, pA, pB, pC, flags, out);
    } else {
        // fallback: r9 4-launch path (needs 25 MB; minimal variant pings pA)
        evolve_kernel<0><<<BSZ * NT, 512, 0, stream>>>(base, upar, lcu, pA, pc, acc, 0);
        evolve_kernel<1><<<BSZ * NT, 512, 0, stream>>>(pA,   upar, lcu, pA, pc, acc, 1);
        evolve_kernel<1><<<BSZ * NT, 512, 0, stream>>>(pA,   upar, lcu, pA, pc, acc, 2);
        final_kernel<<<BSZ * 8, 256, 0, stream>>>(pA, pc, acc, out);
    }
}

// Round 15
// 245.632 us; speedup vs baseline: 1.5301x; 1.5301x over previous
//
#include <hip/hip_runtime.h>
#include <utility>

#define DIM 2048
#define NQ 11
#define NROT 88
#define BSZ 64
#define NT 8
#define NPC 4   // DEGREE+1

#if __has_builtin(__builtin_amdgcn_permlane16_swap)
#define HAVE_PL16 1
#else
#define HAVE_PL16 0
#endif
#if __has_builtin(__builtin_amdgcn_permlane32_swap)
#define HAVE_PL32 1
#else
#define HAVE_PL32 0
#endif

// ---------------------------------------------------------------------------
// Compile-time gate schedule. Gate G in [0,88); wire w <-> state bit 10-w.
// ---------------------------------------------------------------------------
constexpr int g_type(int G) {
    int j = G % 44;
    return (j < 11 || (j >= 22 && j < 33)) ? 0 : 1;   // 0=RY, 1=CRX
}
constexpr int g_pt(int G) {
    int j = G % 44;
    if (j < 11) return 10 - j;
    if (j < 22) { int i = 21 - j; int tw = (i + 1 == NQ) ? 0 : i + 1; return 10 - tw; }
    if (j < 33) return 10 - (j - 22);
    if (j == 33) return 1;
    int i = j - 34; int tw = (i + 10) % NQ; return 10 - tw;
}
constexpr int g_pcb(int G) {
    int j = G % 44;
    if (j >= 11 && j < 22) { int i = 21 - j; return 10 - i; }
    if (j == 33) return 0;
    if (j >= 34) { int i = j - 34; return 10 - i; }
    return -1;  // RY
}
constexpr bool use_sum_tier(int lb) {
    return (lb == 4 && HAVE_PL16) || (lb == 5 && HAVE_PL32);
}

// Transposed-layout bit map: swap state bits 2<->8, 3<->9, 5<->10 (r9-proven).
constexpr int tmap(int b) {
    if (b == 2) return 8;  if (b == 8) return 2;
    if (b == 3) return 9;  if (b == 9) return 3;
    if (b == 5) return 10; if (b == 10) return 5;
    return b;
}

// ---------------------------------------------------------------------------
// Per-layer op schedule (48 ops: 44 gates + 4 transposes), r9-proven.
// ---------------------------------------------------------------------------
constexpr int lop_j(int k) {
    if (k < 8)  return 3 + k;
    if (k == 8) return -1;
    if (k < 12) return k - 9;
    if (k == 12) return 11;
    if (k == 13) return -1;
    if (k < 22) return 12 + (k - 14);
    if (k == 22) return -1;
    if (k == 23) return 20;
    if (k == 24) return 21;
    if (k < 31) { int w[6] = {0, 1, 2, 3, 9, 10}; return 22 + w[k - 25]; }
    if (k < 36) return 33 + (k - 31);
    if (k == 36) return -1;
    if (k < 42) return 26 + (k - 37);
    return 38 + (k - 42);
}
constexpr bool lop_B(int k) {
    return (k >= 9 && k <= 12) || (k >= 23 && k <= 35);
}
constexpr int lop_tpar(int k) { return (k == 8 || k == 22) ? 0 : 1; }

// ---------------------------------------------------------------------------
// Wave-uniform trig fetch via readlane.
// ---------------------------------------------------------------------------
template<int G>
__device__ __forceinline__ void get_cs(float c0, float s0, float c1, float s1,
                                       float& c, float& s) {
    if constexpr (G < 64) {
        c = __int_as_float(__builtin_amdgcn_readlane(__float_as_int(c0), G));
        s = __int_as_float(__builtin_amdgcn_readlane(__float_as_int(s0), G));
    } else {
        c = __int_as_float(__builtin_amdgcn_readlane(__float_as_int(c1), G - 64));
        s = __int_as_float(__builtin_amdgcn_readlane(__float_as_int(s1), G - 64));
    }
}

// ---------------------------------------------------------------------------
// Lane exchange across tid bit LB (state bit LB+2) — PARTNER form.
// ---------------------------------------------------------------------------
template<int LB>
__device__ __forceinline__ float lxp(float x) {
    if constexpr (LB == 0) {
        return __int_as_float(__builtin_amdgcn_update_dpp(
            __float_as_int(x), __float_as_int(x), 0xB1, 0xF, 0xF, true)); // xor1
    } else if constexpr (LB == 1) {
        return __int_as_float(__builtin_amdgcn_update_dpp(
            __float_as_int(x), __float_as_int(x), 0x4E, 0xF, 0xF, true)); // xor2
    } else if constexpr (LB == 2) {
        return __int_as_float(__builtin_amdgcn_ds_swizzle(__float_as_int(x), 0x101F)); // xor4
    } else if constexpr (LB == 3) {
        return __int_as_float(__builtin_amdgcn_update_dpp(
            __float_as_int(x), __float_as_int(x), 0x128, 0xF, 0xF, true)); // row_ror:8 = xor8
    } else if constexpr (LB == 4) {
        return __int_as_float(__builtin_amdgcn_ds_swizzle(__float_as_int(x), 0x401F)); // xor16
    } else {
        return __shfl_xor(x, 32, 64);                                                  // xor32
    }
}

// Fused exchange+multiply+accumulate: acc += partner_across_LB(src) * coef.
// v_fmac_f32_dpp: single VALU instruction (DPP on S0, coef in VGPR S1).
template<int LB>
__device__ __forceinline__ void fmac_dpp(float& acc, float src, float coef) {
    if constexpr (LB == 0) {
        asm("v_fmac_f32_dpp %0, %2, %3 quad_perm:[1,0,3,2] row_mask:0xf bank_mask:0xf"
            : "=v"(acc) : "0"(acc), "v"(src), "v"(coef));
    } else if constexpr (LB == 1) {
        asm("v_fmac_f32_dpp %0, %2, %3 quad_perm:[2,3,0,1] row_mask:0xf bank_mask:0xf"
            : "=v"(acc) : "0"(acc), "v"(src), "v"(coef));
    } else {
        asm("v_fmac_f32_dpp %0, %2, %3 row_ror:8 row_mask:0xf bank_mask:0xf"
            : "=v"(acc) : "0"(acc), "v"(src), "v"(coef));
    }
}

// SUM form: returns own + partner (order-immune to permlane*_swap ordering).
template<int LB>
__device__ __forceinline__ float lxsum(float x) {
#if HAVE_PL16
    if constexpr (LB == 4) {
        unsigned u = __float_as_uint(x);
        auto r = __builtin_amdgcn_permlane16_swap(u, u, false, false);
        return __uint_as_float(r[0]) + __uint_as_float(r[1]);
    }
#endif
#if HAVE_PL32
    if constexpr (LB == 5) {
        unsigned u = __float_as_uint(x);
        auto r = __builtin_amdgcn_permlane32_swap(u, u, false, false);
        return __uint_as_float(r[0]) + __uint_as_float(r[1]);
    }
#endif
    return x + lxp<LB>(x);
}

// ---------------------------------------------------------------------------
// Layout: 512 threads, thread tid holds amps a = tid*4 + (2m+e), m,e in {0,1}.
//   amp bits: 0=e, 1=m, 2..7=lane(tid 0..5), 8..10=block(tid 6..8)
// Layout B via transpose: bits (2,3,5) <-> (8,9,10).  [r9-proven]
// ---------------------------------------------------------------------------
template<int G, bool PB>
__device__ __forceinline__ void apply_gate(
    float2 (&R)[2], float2 (&I)[2],
    float c0, float s0, float c1, float s1, const int tid)
{
    constexpr int type = g_type(G);
    constexpr int pt   = PB ? tmap(g_pt(G)) : g_pt(G);
    constexpr int pcb0 = g_pcb(G);
    constexpr int pcb  = (pcb0 < 0) ? -1 : (PB ? tmap(pcb0) : pcb0);
    static_assert(pt <= 7, "block-bit target must run in transposed layout");
    float c, s;
    get_cs<G>(c0, s0, c1, s1, c, s);

    if constexpr (pt == 0) {
        if constexpr (type == 0) {
#pragma unroll
            for (int m = 0; m < 2; ++m) {
                float er = R[m].x, orr = R[m].y, ei = I[m].x, oi = I[m].y;
                R[m].x = c*er - s*orr;  R[m].y = s*er + c*orr;
                I[m].x = c*ei - s*oi;   I[m].y = s*ei + c*oi;
            }
        } else if constexpr (pcb == 1) {
            float er = R[1].x, orr = R[1].y, ei = I[1].x, oi = I[1].y;
            R[1].x = c*er + s*oi;   I[1].x = c*ei - s*orr;
            R[1].y = c*orr + s*ei;  I[1].y = c*oi - s*er;
        } else {
            const bool ctrl = (tid >> (pcb - 2)) & 1;
            if (ctrl) {
#pragma unroll
                for (int m = 0; m < 2; ++m) {
                    float er = R[m].x, orr = R[m].y, ei = I[m].x, oi = I[m].y;
                    R[m].x = c*er + s*oi;   I[m].x = c*ei - s*orr;
                    R[m].y = c*orr + s*ei;  I[m].y = c*oi - s*er;
                }
            }
        }
    } else if constexpr (pt == 1) {
        if constexpr (type == 0) {
            float2 l = R[0], h = R[1], li = I[0], hi = I[1];
            R[0].x = c*l.x - s*h.x;   R[0].y = c*l.y - s*h.y;
            R[1].x = s*l.x + c*h.x;   R[1].y = s*l.y + c*h.y;
            I[0].x = c*li.x - s*hi.x; I[0].y = c*li.y - s*hi.y;
            I[1].x = s*li.x + c*hi.x; I[1].y = s*li.y + c*hi.y;
        } else if constexpr (pcb == 0) {
            float lr = R[0].y, li = I[0].y, hr = R[1].y, hi = I[1].y;
            R[0].y = c*lr + s*hi;   I[0].y = c*li - s*hr;
            R[1].y = c*hr + s*li;   I[1].y = c*hi - s*lr;
        } else {
            const bool ctrl = (tid >> (pcb - 2)) & 1;
            if (ctrl) {
                float2 l = R[0], h = R[1], li = I[0], hi = I[1];
                R[0].x = c*l.x + s*hi.x;  R[0].y = c*l.y + s*hi.y;
                I[0].x = c*li.x - s*h.x;  I[0].y = c*li.y - s*h.y;
                R[1].x = c*h.x + s*li.x;  R[1].y = c*h.y + s*li.y;
                I[1].x = c*hi.x - s*l.x;  I[1].y = c*hi.y - s*l.y;
            }
        }
    } else {
        constexpr int lb = pt - 2;
        constexpr bool dppable = (lb == 0 || lb == 1 || lb == 3);
        if constexpr (use_sum_tier(lb)) {
            if constexpr (type == 0) {
                const float sg = ((tid >> lb) & 1) ? s : -s;
                const float k1 = c - sg;
#pragma unroll
                for (int m = 0; m < 2; ++m) {
                    float srx = lxsum<lb>(R[m].x), sry = lxsum<lb>(R[m].y);
                    float six = lxsum<lb>(I[m].x), siy = lxsum<lb>(I[m].y);
                    R[m].x = k1*R[m].x + sg*srx;  R[m].y = k1*R[m].y + sg*sry;
                    I[m].x = k1*I[m].x + sg*six;  I[m].y = k1*I[m].y + sg*siy;
                }
            } else if constexpr (pcb == 0) {
#pragma unroll
                for (int m = 0; m < 2; ++m) {
                    float sR = lxsum<lb>(R[m].y), sI = lxsum<lb>(I[m].y);
                    float r = R[m].y, i = I[m].y;
                    R[m].y = c*r - s*i + s*sI;
                    I[m].y = c*i + s*r - s*sR;
                }
            } else if constexpr (pcb == 1) {
                float sRx = lxsum<lb>(R[1].x), sRy = lxsum<lb>(R[1].y);
                float sIx = lxsum<lb>(I[1].x), sIy = lxsum<lb>(I[1].y);
                float rx = R[1].x, ry = R[1].y, ix = I[1].x, iy = I[1].y;
                R[1].x = c*rx - s*ix + s*sIx;  R[1].y = c*ry - s*iy + s*sIy;
                I[1].x = c*ix + s*rx - s*sRx;  I[1].y = c*iy + s*ry - s*sRy;
            } else {
                const bool ctrl = (tid >> (pcb - 2)) & 1;
                if (ctrl) {
#pragma unroll
                    for (int m = 0; m < 2; ++m) {
                        float sRx = lxsum<lb>(R[m].x), sRy = lxsum<lb>(R[m].y);
                        float sIx = lxsum<lb>(I[m].x), sIy = lxsum<lb>(I[m].y);
                        float rx = R[m].x, ry = R[m].y, ix = I[m].x, iy = I[m].y;
                        R[m].x = c*rx - s*ix + s*sIx;  R[m].y = c*ry - s*iy + s*sIy;
                        I[m].x = c*ix + s*rx - s*sRx;  I[m].y = c*iy + s*ry - s*sRy;
                    }
                }
            }
        } else if constexpr (dppable) {
            // fused v_fmac_f32_dpp paths: new = c*own + coef*partner
            if constexpr (type == 0) {
                const float sgn = ((tid >> lb) & 1) ? s : -s;
#pragma unroll
                for (int m = 0; m < 2; ++m) {
                    float nrx = c*R[m].x; fmac_dpp<lb>(nrx, R[m].x, sgn);
                    float nry = c*R[m].y; fmac_dpp<lb>(nry, R[m].y, sgn);
                    float nix = c*I[m].x; fmac_dpp<lb>(nix, I[m].x, sgn);
                    float niy = c*I[m].y; fmac_dpp<lb>(niy, I[m].y, sgn);
                    R[m].x = nrx; R[m].y = nry; I[m].x = nix; I[m].y = niy;
                }
            } else if constexpr (pcb == 0) {
                const float vs = s, vns = -s;
#pragma unroll
                for (int m = 0; m < 2; ++m) {
                    float nry = c*R[m].y; fmac_dpp<lb>(nry, I[m].y, vs);
                    float niy = c*I[m].y; fmac_dpp<lb>(niy, R[m].y, vns);
                    R[m].y = nry; I[m].y = niy;
                }
            } else if constexpr (pcb == 1) {
                const float vs = s, vns = -s;
                float nrx = c*R[1].x; fmac_dpp<lb>(nrx, I[1].x, vs);
                float nry = c*R[1].y; fmac_dpp<lb>(nry, I[1].y, vs);
                float nix = c*I[1].x; fmac_dpp<lb>(nix, R[1].x, vns);
                float niy = c*I[1].y; fmac_dpp<lb>(niy, R[1].y, vns);
                R[1].x = nrx; R[1].y = nry; I[1].x = nix; I[1].y = niy;
            } else {
                // ctrl bit != exchange bit -> partner shares ctrl: safe branch
                const bool ctrl = (tid >> (pcb - 2)) & 1;
                if (ctrl) {
                    const float vs = s, vns = -s;
#pragma unroll
                    for (int m = 0; m < 2; ++m) {
                        float nrx = c*R[m].x; fmac_dpp<lb>(nrx, I[m].x, vs);
                        float nry = c*R[m].y; fmac_dpp<lb>(nry, I[m].y, vs);
                        float nix = c*I[m].x; fmac_dpp<lb>(nix, R[m].x, vns);
                        float niy = c*I[m].y; fmac_dpp<lb>(niy, R[m].y, vns);
                        R[m].x = nrx; R[m].y = nry; I[m].x = nix; I[m].y = niy;
                    }
                }
            }
        } else {
            // lb == 2 (ds_swizzle xor4) partner form
            if constexpr (type == 0) {
                const float sg = ((tid >> lb) & 1) ? s : -s;
#pragma unroll
                for (int m = 0; m < 2; ++m) {
                    float prx = lxp<lb>(R[m].x), pry = lxp<lb>(R[m].y);
                    float pix = lxp<lb>(I[m].x), piy = lxp<lb>(I[m].y);
                    R[m].x = c*R[m].x + sg*prx;  R[m].y = c*R[m].y + sg*pry;
                    I[m].x = c*I[m].x + sg*pix;  I[m].y = c*I[m].y + sg*piy;
                }
            } else if constexpr (pcb == 0) {
#pragma unroll
                for (int m = 0; m < 2; ++m) {
                    float pry = lxp<lb>(R[m].y), piy = lxp<lb>(I[m].y);
                    R[m].y = c*R[m].y + s*piy;
                    I[m].y = c*I[m].y - s*pry;
                }
            } else if constexpr (pcb == 1) {
                float prx = lxp<lb>(R[1].x), pry = lxp<lb>(R[1].y);
                float pix = lxp<lb>(I[1].x), piy = lxp<lb>(I[1].y);
                R[1].x = c*R[1].x + s*pix;  R[1].y = c*R[1].y + s*piy;
                I[1].x = c*I[1].x - s*prx;  I[1].y = c*I[1].y - s*pry;
            } else {
                const bool ctrl = (tid >> (pcb - 2)) & 1;
                if (ctrl) {
#pragma unroll
                    for (int m = 0; m < 2; ++m) {
                        float prx = lxp<lb>(R[m].x), pry = lxp<lb>(R[m].y);
                        float pix = lxp<lb>(I[m].x), piy = lxp<lb>(I[m].y);
                        R[m].x = c*R[m].x + s*pix;  R[m].y = c*R[m].y + s*piy;
                        I[m].x = c*I[m].x - s*prx;  I[m].y = c*I[m].y - s*pry;
                    }
                }
            }
        }
    }
}

// ---------------------------------------------------------------------------
// Whole-payload thread transpose: swap tid bits (0,1,3) <-> (6,7,8) via LDS.
// ---------------------------------------------------------------------------
__device__ __forceinline__ int swz(int s) { return s ^ ((s >> 7) & 7); }

template<int PAR>
__device__ __forceinline__ void transpose_swap(float2 (&R)[2], float2 (&I)[2],
                                               float4* __restrict__ exbuf, const int tid)
{
    float4* buf = exbuf + PAR * 1024;
    const int d06 = ((tid >> 0) ^ (tid >> 6)) & 1;
    const int d17 = ((tid >> 1) ^ (tid >> 7)) & 1;
    const int d38 = ((tid >> 3) ^ (tid >> 8)) & 1;
    const int q = tid ^ (d06 * 65) ^ (d17 * 130) ^ (d38 * 264);
    buf[swz(tid * 2 + 0)] = make_float4(R[0].x, R[0].y, I[0].x, I[0].y);
    buf[swz(tid * 2 + 1)] = make_float4(R[1].x, R[1].y, I[1].x, I[1].y);
    __syncthreads();
    float4 v0 = buf[swz(q * 2 + 0)];
    float4 v1 = buf[swz(q * 2 + 1)];
    R[0] = make_float2(v0.x, v0.y); I[0] = make_float2(v0.z, v0.w);
    R[1] = make_float2(v1.x, v1.y); I[1] = make_float2(v1.z, v1.w);
    // no trailing barrier: parity buffer reused 2 transposes later; the
    // intervening transpose's barrier orders those reads before writes.
}

// ---------------------------------------------------------------------------
// Op dispatcher over the 96-op schedule (2 layers x 48).
// ---------------------------------------------------------------------------
template<int K>
__device__ __forceinline__ void apply_op(
    float2 (&R)[2], float2 (&I)[2],
    float c0, float s0, float c1, float s1,
    float4* __restrict__ exbuf, const int tid)
{
    constexpr int layer = K / 48;
    constexpr int k = K % 48;
    constexpr int j = lop_j(k);
    if constexpr (j < 0) {
        transpose_swap<lop_tpar(k)>(R, I, exbuf, tid);
    } else {
        apply_gate<layer * 44 + j, lop_B(k)>(R, I, c0, s0, c1, s1, tid);
    }
}

template<int... Ks>
__device__ __forceinline__ void apply_all(std::integer_sequence<int, Ks...>,
    float2 (&R)[2], float2 (&I)[2],
    float c0, float s0, float c1, float s1,
    float4* __restrict__ exbuf, const int tid)
{
    (apply_op<Ks>(R, I, c0, s0, c1, s1, exbuf, tid), ...);
}

__device__ __forceinline__ void evolve_once(float2 (&R)[2], float2 (&I)[2],
    float c0, float s0, float c1, float s1,
    float4* __restrict__ exbuf, const int tid)
{
    apply_all(std::make_integer_sequence<int, 96>{}, R, I, c0, s0, c1, s1, exbuf, tid);
}

// ---------------------------------------------------------------------------
// Evolve. MODE 0: src = base (normalize inline, t==0 inits acc).
// MODE 1: src = prev partials (inline-reduce; t==0 folds pc[kprev] into acc).
// DO_FINAL: after writing pout, last-arriving block of each b computes out
// (each thread covers TWO float4 slots: jj = tid, tid+512 -> all 2048 amps).
// ---------------------------------------------------------------------------
template<int MODE, bool DO_FINAL>
__global__ __launch_bounds__(512, 4) void evolve_kernel(
    const void* __restrict__ src, const float* __restrict__ uparams,
    const float* __restrict__ lcu, float2* __restrict__ pout,
    const float* __restrict__ pcoef, float2* __restrict__ acc, int kprev,
    int* __restrict__ cnt, float* __restrict__ out)
{
    __shared__ float4 exbuf[2048];
    __shared__ float red[9];
    __shared__ int sLast;

    const int b = blockIdx.x >> 3;
    const int t = blockIdx.x & 7;
    const int tid = threadIdx.x;
    const int lane = tid & 63;

    const float* __restrict__ th_row = uparams + (size_t)(b * NT + t) * NROT;
    float th0 = 0.5f * th_row[lane];
    float th1 = (lane < NROT - 64) ? 0.5f * th_row[64 + lane] : 0.f;
    float tc0 = cosf(th0), ts0 = sinf(th0);
    float tc1 = cosf(th1), ts1 = sinf(th1);

    float2 R[2], I[2];
    if constexpr (MODE == 0) {
        const float4* b4 = (const float4*)((const float*)src + (size_t)b * DIM);
        float4 v = b4[tid];
        float loc = v.x*v.x + v.y*v.y + v.z*v.z + v.w*v.w;
        for (int off = 32; off > 0; off >>= 1) loc += __shfl_down(loc, off, 64);
        if ((tid & 63) == 0) red[tid >> 6] = loc;
        __syncthreads();
        if (tid == 0) { float sm = 0.f; for (int w = 0; w < 8; ++w) sm += red[w]; red[8] = sm; }
        __syncthreads();
        const float inv = rsqrtf(red[8]);
        R[0] = make_float2(v.x * inv, v.y * inv);
        R[1] = make_float2(v.z * inv, v.w * inv);
        I[0] = make_float2(0.f, 0.f);
        I[1] = make_float2(0.f, 0.f);
        if (t == 0) {
            const float p0 = pcoef[0];
            float4* a4 = (float4*)(acc + (size_t)b * DIM);
            a4[tid*2+0] = make_float4(p0*R[0].x, 0.f, p0*R[0].y, 0.f);
            a4[tid*2+1] = make_float4(p0*R[1].x, 0.f, p0*R[1].y, 0.f);
        }
        __syncthreads();
    } else {
        R[0] = make_float2(0.f, 0.f); R[1] = make_float2(0.f, 0.f);
        I[0] = make_float2(0.f, 0.f); I[1] = make_float2(0.f, 0.f);
        const float2* s2 = (const float2*)src;
        for (int cc = 0; cc < NT; ++cc) {
            const float4* p4 = (const float4*)(s2 + ((size_t)b * NT + cc) * DIM);
#pragma unroll
            for (int m = 0; m < 2; ++m) {
                float4 v = p4[tid*2+m];
                R[m].x += v.x; I[m].x += v.y; R[m].y += v.z; I[m].y += v.w;
            }
        }
        if (t == 0 && kprev > 0) {
            const float pk = pcoef[kprev];
            float4* a4 = (float4*)(acc + (size_t)b * DIM);
#pragma unroll
            for (int m = 0; m < 2; ++m) {
                float4 v = a4[tid*2+m];
                v.x += pk * R[m].x; v.y += pk * I[m].x;
                v.z += pk * R[m].y; v.w += pk * I[m].y;
                a4[tid*2+m] = v;
            }
        }
    }

    evolve_once(R, I, tc0, ts0, tc1, ts1, exbuf, tid);

    const float coeff = lcu[b * NT + t];
    float4* o4 = (float4*)(pout + ((size_t)b * NT + t) * DIM);
#pragma unroll
    for (int m = 0; m < 2; ++m)
        o4[tid*2+m] = make_float4(coeff*R[m].x, coeff*I[m].x, coeff*R[m].y, coeff*I[m].y);

    if constexpr (DO_FINAL) {
        __threadfence();                  // publish this block's pout + acc writes
        __syncthreads();
        if (tid == 0) {
            int old = __hip_atomic_fetch_add(&cnt[b], 1, __ATOMIC_ACQ_REL,
                                             __HIP_MEMORY_SCOPE_AGENT);
            sLast = (old == NT - 1) ? 1 : 0;
        }
        __syncthreads();
        if (sLast) {
            __threadfence();              // acquire side: see all 8 blocks' writes
            float sabs = 0.f;
            for (int q = 0; q < NPC; ++q) sabs += fabsf(pcoef[q]);
            const float invn = 1.0f / sabs;
            const float pk = pcoef[NPC - 1];
            float4* outv = (float4*)(out + (size_t)b * DIM * 2);
            const float4* accv = (const float4*)(acc + (size_t)b * DIM);
#pragma unroll
            for (int jj = tid; jj < DIM / 2; jj += 512) {
                float4 sum = make_float4(0.f, 0.f, 0.f, 0.f);
                for (int cc = 0; cc < NT; ++cc) {
                    float4 v = ((const float4*)(pout + ((size_t)b * NT + cc) * DIM))[jj];
                    sum.x += v.x; sum.y += v.y; sum.z += v.z; sum.w += v.w;
                }
                float4 a = accv[jj];
                outv[jj] = make_float4((a.x + pk*sum.x) * invn, (a.y + pk*sum.y) * invn,
                                       (a.z + pk*sum.z) * invn, (a.w + pk*sum.w) * invn);
            }
        }
    }
}

extern "C" void kernel_launch(void* const* d_in, const int* in_sizes, int n_in,
                              void* d_out, int out_size, void* d_ws, size_t ws_size,
                              hipStream_t stream) {
    const float* base = (const float*)d_in[0];   // (64, 2048) f32
    const float* upar = (const float*)d_in[1];   // (64, 8, 88) f32
    const float* lcu  = (const float*)d_in[2];   // (64, 8) f32
    const float* pc   = (const float*)d_in[3];   // (4,) f32
    float* out = (float*)d_out;                  // (64, 2048, 2) f32

    const size_t plane = (size_t)BSZ * DIM * sizeof(float2);   // 1 MB
    const size_t cnt_bytes = (size_t)BSZ * sizeof(int);
    char* ws = (char*)d_ws;

    float2* acc = (float2*)ws;
    float2* pA  = (float2*)(ws + plane);
    float2* pB  = (float2*)(ws + plane + (size_t)NT * plane);
    float2* pC  = (float2*)(ws + plane + (size_t)2 * NT * plane);
    int* cnt    = (int*)(ws + plane + (size_t)3 * NT * plane);

    if (ws_size >= (1 + 3 * (size_t)NT) * plane + cnt_bytes) {
        hipMemsetAsync(cnt, 0, cnt_bytes, stream);
        evolve_kernel<0, false><<<BSZ * NT, 512, 0, stream>>>(
            base, upar, lcu, pA, pc, acc, 0, nullptr, nullptr);
        evolve_kernel<1, false><<<BSZ * NT, 512, 0, stream>>>(
            pA, upar, lcu, pB, pc, acc, 1, nullptr, nullptr);
        evolve_kernel<1, true><<<BSZ * NT, 512, 0, stream>>>(
            pB, upar, lcu, pC, pc, acc, 2, cnt, out);
    } else {
        // compact fallback: alternate pA/pB (needs 1+2*NT MB + cnt)
        float2* qA = (float2*)(ws + plane);
        float2* qB = (float2*)(ws + plane + (size_t)NT * plane);
        int* c2    = (int*)(ws + plane + (size_t)2 * NT * plane);
        hipMemsetAsync(c2, 0, cnt_bytes, stream);
        evolve_kernel<0, false><<<BSZ * NT, 512, 0, stream>>>(
            base, upar, lcu, qA, pc, acc, 0, nullptr, nullptr);
        evolve_kernel<1, false><<<BSZ * NT, 512, 0, stream>>>(
            qA, upar, lcu, qB, pc, acc, 1, nullptr, nullptr);
        evolve_kernel<1, true><<<BSZ * NT, 512, 0, stream>>>(
            qB, upar, lcu, qA, pc, acc, 2, c2, out);
    }
}

// Round 16
// 245.349 us; speedup vs baseline: 1.5319x; 1.0012x over previous
//
#include <hip/hip_runtime.h>
#include <utility>

#define DIM 2048
#define NQ 11
#define NROT 88
#define BSZ 64
#define NT 8
#define NPC 4   // DEGREE+1

#if __has_builtin(__builtin_amdgcn_permlane16_swap)
#define HAVE_PL16 1
#else
#define HAVE_PL16 0
#endif
#if __has_builtin(__builtin_amdgcn_permlane32_swap)
#define HAVE_PL32 1
#else
#define HAVE_PL32 0
#endif

// ---------------------------------------------------------------------------
// Compile-time gate schedule. Gate G in [0,88); wire w <-> state bit 10-w.
// ---------------------------------------------------------------------------
constexpr int g_type(int G) {
    int j = G % 44;
    return (j < 11 || (j >= 22 && j < 33)) ? 0 : 1;   // 0=RY, 1=CRX
}
constexpr int g_pt(int G) {
    int j = G % 44;
    if (j < 11) return 10 - j;
    if (j < 22) { int i = 21 - j; int tw = (i + 1 == NQ) ? 0 : i + 1; return 10 - tw; }
    if (j < 33) return 10 - (j - 22);
    if (j == 33) return 1;
    int i = j - 34; int tw = (i + 10) % NQ; return 10 - tw;
}
constexpr int g_pcb(int G) {
    int j = G % 44;
    if (j >= 11 && j < 22) { int i = 21 - j; return 10 - i; }
    if (j == 33) return 0;
    if (j >= 34) { int i = j - 34; return 10 - i; }
    return -1;  // RY
}
constexpr bool use_sum_tier(int lb) {
    return (lb == 4 && HAVE_PL16) || (lb == 5 && HAVE_PL32);
}

// Transposed-layout bit map: swap state bits 2<->8, 3<->9, 5<->10 (proven).
constexpr int tmap(int b) {
    if (b == 2) return 8;  if (b == 8) return 2;
    if (b == 3) return 9;  if (b == 9) return 3;
    if (b == 5) return 10; if (b == 10) return 5;
    return b;
}

// ---------------------------------------------------------------------------
// Per-layer op schedule (48 ops: 44 gates + 4 transposes), proven @85.2us.
// ---------------------------------------------------------------------------
constexpr int lop_j(int k) {
    if (k < 8)  return 3 + k;
    if (k == 8) return -1;
    if (k < 12) return k - 9;
    if (k == 12) return 11;
    if (k == 13) return -1;
    if (k < 22) return 12 + (k - 14);
    if (k == 22) return -1;
    if (k == 23) return 20;
    if (k == 24) return 21;
    if (k < 31) { int w[6] = {0, 1, 2, 3, 9, 10}; return 22 + w[k - 25]; }
    if (k < 36) return 33 + (k - 31);
    if (k == 36) return -1;
    if (k < 42) return 26 + (k - 37);
    return 38 + (k - 42);
}
constexpr bool lop_B(int k) {
    return (k >= 9 && k <= 12) || (k >= 23 && k <= 35);
}
constexpr int lop_tpar(int k) { return (k == 8 || k == 22) ? 0 : 1; }

// ---------------------------------------------------------------------------
// Wave-uniform trig fetch via readlane.
// ---------------------------------------------------------------------------
template<int G>
__device__ __forceinline__ void get_cs(float c0, float s0, float c1, float s1,
                                       float& c, float& s) {
    if constexpr (G < 64) {
        c = __int_as_float(__builtin_amdgcn_readlane(__float_as_int(c0), G));
        s = __int_as_float(__builtin_amdgcn_readlane(__float_as_int(s0), G));
    } else {
        c = __int_as_float(__builtin_amdgcn_readlane(__float_as_int(c1), G - 64));
        s = __int_as_float(__builtin_amdgcn_readlane(__float_as_int(s1), G - 64));
    }
}

// ---------------------------------------------------------------------------
// Lane exchange across tid bit LB (state bit LB+2) — PARTNER form.
// ---------------------------------------------------------------------------
template<int LB>
__device__ __forceinline__ float lxp(float x) {
    if constexpr (LB == 0) {
        return __int_as_float(__builtin_amdgcn_update_dpp(
            __float_as_int(x), __float_as_int(x), 0xB1, 0xF, 0xF, true)); // xor1
    } else if constexpr (LB == 1) {
        return __int_as_float(__builtin_amdgcn_update_dpp(
            __float_as_int(x), __float_as_int(x), 0x4E, 0xF, 0xF, true)); // xor2
    } else if constexpr (LB == 2) {
        return __int_as_float(__builtin_amdgcn_ds_swizzle(__float_as_int(x), 0x101F)); // xor4
    } else if constexpr (LB == 3) {
        return __int_as_float(__builtin_amdgcn_update_dpp(
            __float_as_int(x), __float_as_int(x), 0x128, 0xF, 0xF, true)); // row_ror:8 = xor8
    } else if constexpr (LB == 4) {
        return __int_as_float(__builtin_amdgcn_ds_swizzle(__float_as_int(x), 0x401F)); // xor16
    } else {
        return __shfl_xor(x, 32, 64);                                                  // xor32
    }
}

// SUM form: returns own + partner (order-immune to permlane*_swap ordering).
template<int LB>
__device__ __forceinline__ float lxsum(float x) {
#if HAVE_PL16
    if constexpr (LB == 4) {
        unsigned u = __float_as_uint(x);
        auto r = __builtin_amdgcn_permlane16_swap(u, u, false, false);
        return __uint_as_float(r[0]) + __uint_as_float(r[1]);
    }
#endif
#if HAVE_PL32
    if constexpr (LB == 5) {
        unsigned u = __float_as_uint(x);
        auto r = __builtin_amdgcn_permlane32_swap(u, u, false, false);
        return __uint_as_float(r[0]) + __uint_as_float(r[1]);
    }
#endif
    return x + lxp<LB>(x);
}

// ---------------------------------------------------------------------------
// Layout: 512 threads, thread tid holds amps a = tid*4 + (2m+e), m,e in {0,1}.
//   amp bits: 0=e, 1=m, 2..7=lane(tid 0..5), 8..10=block(tid 6..8)
// Layout B via transpose: bits (2,3,5) <-> (8,9,10).  [proven 85.2us body]
// ---------------------------------------------------------------------------
template<int G, bool PB>
__device__ __forceinline__ void apply_gate(
    float2 (&R)[2], float2 (&I)[2],
    float c0, float s0, float c1, float s1, const int tid)
{
    constexpr int type = g_type(G);
    constexpr int pt   = PB ? tmap(g_pt(G)) : g_pt(G);
    constexpr int pcb0 = g_pcb(G);
    constexpr int pcb  = (pcb0 < 0) ? -1 : (PB ? tmap(pcb0) : pcb0);
    static_assert(pt <= 7, "block-bit target must run in transposed layout");
    float c, s;
    get_cs<G>(c0, s0, c1, s1, c, s);

    if constexpr (pt == 0) {
        if constexpr (type == 0) {
#pragma unroll
            for (int m = 0; m < 2; ++m) {
                float er = R[m].x, orr = R[m].y, ei = I[m].x, oi = I[m].y;
                R[m].x = c*er - s*orr;  R[m].y = s*er + c*orr;
                I[m].x = c*ei - s*oi;   I[m].y = s*ei + c*oi;
            }
        } else if constexpr (pcb == 1) {
            float er = R[1].x, orr = R[1].y, ei = I[1].x, oi = I[1].y;
            R[1].x = c*er + s*oi;   I[1].x = c*ei - s*orr;
            R[1].y = c*orr + s*ei;  I[1].y = c*oi - s*er;
        } else {
            const bool ctrl = (tid >> (pcb - 2)) & 1;
            if (ctrl) {
#pragma unroll
                for (int m = 0; m < 2; ++m) {
                    float er = R[m].x, orr = R[m].y, ei = I[m].x, oi = I[m].y;
                    R[m].x = c*er + s*oi;   I[m].x = c*ei - s*orr;
                    R[m].y = c*orr + s*ei;  I[m].y = c*oi - s*er;
                }
            }
        }
    } else if constexpr (pt == 1) {
        if constexpr (type == 0) {
            float2 l = R[0], h = R[1], li = I[0], hi = I[1];
            R[0].x = c*l.x - s*h.x;   R[0].y = c*l.y - s*h.y;
            R[1].x = s*l.x + c*h.x;   R[1].y = s*l.y + c*h.y;
            I[0].x = c*li.x - s*hi.x; I[0].y = c*li.y - s*hi.y;
            I[1].x = s*li.x + c*hi.x; I[1].y = s*li.y + c*hi.y;
        } else if constexpr (pcb == 0) {
            float lr = R[0].y, li = I[0].y, hr = R[1].y, hi = I[1].y;
            R[0].y = c*lr + s*hi;   I[0].y = c*li - s*hr;
            R[1].y = c*hr + s*li;   I[1].y = c*hi - s*lr;
        } else {
            const bool ctrl = (tid >> (pcb - 2)) & 1;
            if (ctrl) {
                float2 l = R[0], h = R[1], li = I[0], hi = I[1];
                R[0].x = c*l.x + s*hi.x;  R[0].y = c*l.y + s*hi.y;
                I[0].x = c*li.x - s*h.x;  I[0].y = c*li.y - s*h.y;
                R[1].x = c*h.x + s*li.x;  R[1].y = c*h.y + s*li.y;
                I[1].x = c*hi.x - s*l.x;  I[1].y = c*hi.y - s*l.y;
            }
        }
    } else {
        constexpr int lb = pt - 2;
        if constexpr (use_sum_tier(lb)) {
            if constexpr (type == 0) {
                const float sg = ((tid >> lb) & 1) ? s : -s;
                const float k1 = c - sg;
#pragma unroll
                for (int m = 0; m < 2; ++m) {
                    float srx = lxsum<lb>(R[m].x), sry = lxsum<lb>(R[m].y);
                    float six = lxsum<lb>(I[m].x), siy = lxsum<lb>(I[m].y);
                    R[m].x = k1*R[m].x + sg*srx;  R[m].y = k1*R[m].y + sg*sry;
                    I[m].x = k1*I[m].x + sg*six;  I[m].y = k1*I[m].y + sg*siy;
                }
            } else if constexpr (pcb == 0) {
#pragma unroll
                for (int m = 0; m < 2; ++m) {
                    float sR = lxsum<lb>(R[m].y), sI = lxsum<lb>(I[m].y);
                    float r = R[m].y, i = I[m].y;
                    R[m].y = c*r - s*i + s*sI;
                    I[m].y = c*i + s*r - s*sR;
                }
            } else if constexpr (pcb == 1) {
                float sRx = lxsum<lb>(R[1].x), sRy = lxsum<lb>(R[1].y);
                float sIx = lxsum<lb>(I[1].x), sIy = lxsum<lb>(I[1].y);
                float rx = R[1].x, ry = R[1].y, ix = I[1].x, iy = I[1].y;
                R[1].x = c*rx - s*ix + s*sIx;  R[1].y = c*ry - s*iy + s*sIy;
                I[1].x = c*ix + s*rx - s*sRx;  I[1].y = c*iy + s*ry - s*sRy;
            } else {
                const bool ctrl = (tid >> (pcb - 2)) & 1;
                if (ctrl) {
#pragma unroll
                    for (int m = 0; m < 2; ++m) {
                        float sRx = lxsum<lb>(R[m].x), sRy = lxsum<lb>(R[m].y);
                        float sIx = lxsum<lb>(I[m].x), sIy = lxsum<lb>(I[m].y);
                        float rx = R[m].x, ry = R[m].y, ix = I[m].x, iy = I[m].y;
                        R[m].x = c*rx - s*ix + s*sIx;  R[m].y = c*ry - s*iy + s*sIy;
                        I[m].x = c*ix + s*rx - s*sRx;  I[m].y = c*iy + s*ry - s*sRy;
                    }
                }
            }
        } else {
            if constexpr (type == 0) {
                const float sg = ((tid >> lb) & 1) ? s : -s;
#pragma unroll
                for (int m = 0; m < 2; ++m) {
                    float prx = lxp<lb>(R[m].x), pry = lxp<lb>(R[m].y);
                    float pix = lxp<lb>(I[m].x), piy = lxp<lb>(I[m].y);
                    R[m].x = c*R[m].x + sg*prx;  R[m].y = c*R[m].y + sg*pry;
                    I[m].x = c*I[m].x + sg*pix;  I[m].y = c*I[m].y + sg*piy;
                }
            } else if constexpr (pcb == 0) {
#pragma unroll
                for (int m = 0; m < 2; ++m) {
                    float pry = lxp<lb>(R[m].y), piy = lxp<lb>(I[m].y);
                    R[m].y = c*R[m].y + s*piy;
                    I[m].y = c*I[m].y - s*pry;
                }
            } else if constexpr (pcb == 1) {
                float prx = lxp<lb>(R[1].x), pry = lxp<lb>(R[1].y);
                float pix = lxp<lb>(I[1].x), piy = lxp<lb>(I[1].y);
                R[1].x = c*R[1].x + s*pix;  R[1].y = c*R[1].y + s*piy;
                I[1].x = c*I[1].x - s*prx;  I[1].y = c*I[1].y - s*pry;
            } else {
                const bool ctrl = (tid >> (pcb - 2)) & 1;
                if (ctrl) {
#pragma unroll
                    for (int m = 0; m < 2; ++m) {
                        float prx = lxp<lb>(R[m].x), pry = lxp<lb>(R[m].y);
                        float pix = lxp<lb>(I[m].x), piy = lxp<lb>(I[m].y);
                        R[m].x = c*R[m].x + s*pix;  R[m].y = c*R[m].y + s*piy;
                        I[m].x = c*I[m].x - s*prx;  I[m].y = c*I[m].y - s*pry;
                    }
                }
            }
        }
    }
}

// ---------------------------------------------------------------------------
// Whole-payload thread transpose: swap tid bits (0,1,3) <-> (6,7,8) via LDS.
// ---------------------------------------------------------------------------
__device__ __forceinline__ int swz(int s) { return s ^ ((s >> 7) & 7); }

template<int PAR>
__device__ __forceinline__ void transpose_swap(float2 (&R)[2], float2 (&I)[2],
                                               float4* __restrict__ exbuf, const int tid)
{
    float4* buf = exbuf + PAR * 1024;
    const int d06 = ((tid >> 0) ^ (tid >> 6)) & 1;
    const int d17 = ((tid >> 1) ^ (tid >> 7)) & 1;
    const int d38 = ((tid >> 3) ^ (tid >> 8)) & 1;
    const int q = tid ^ (d06 * 65) ^ (d17 * 130) ^ (d38 * 264);
    buf[swz(tid * 2 + 0)] = make_float4(R[0].x, R[0].y, I[0].x, I[0].y);
    buf[swz(tid * 2 + 1)] = make_float4(R[1].x, R[1].y, I[1].x, I[1].y);
    __syncthreads();
    float4 v0 = buf[swz(q * 2 + 0)];
    float4 v1 = buf[swz(q * 2 + 1)];
    R[0] = make_float2(v0.x, v0.y); I[0] = make_float2(v0.z, v0.w);
    R[1] = make_float2(v1.x, v1.y); I[1] = make_float2(v1.z, v1.w);
    // no trailing barrier: parity buffer reused 2 transposes later; the
    // intervening transpose's barrier orders those reads before writes.
}

// ---------------------------------------------------------------------------
// Op dispatcher over the 96-op schedule (2 layers x 48).
// ---------------------------------------------------------------------------
template<int K>
__device__ __forceinline__ void apply_op(
    float2 (&R)[2], float2 (&I)[2],
    float c0, float s0, float c1, float s1,
    float4* __restrict__ exbuf, const int tid)
{
    constexpr int layer = K / 48;
    constexpr int k = K % 48;
    constexpr int j = lop_j(k);
    if constexpr (j < 0) {
        transpose_swap<lop_tpar(k)>(R, I, exbuf, tid);
    } else {
        apply_gate<layer * 44 + j, lop_B(k)>(R, I, c0, s0, c1, s1, tid);
    }
}

template<int... Ks>
__device__ __forceinline__ void apply_all(std::integer_sequence<int, Ks...>,
    float2 (&R)[2], float2 (&I)[2],
    float c0, float s0, float c1, float s1,
    float4* __restrict__ exbuf, const int tid)
{
    (apply_op<Ks>(R, I, c0, s0, c1, s1, exbuf, tid), ...);
}

__device__ __forceinline__ void evolve_once(float2 (&R)[2], float2 (&I)[2],
    float c0, float s0, float c1, float s1,
    float4* __restrict__ exbuf, const int tid)
{
    apply_all(std::make_integer_sequence<int, 96>{}, R, I, c0, s0, c1, s1, exbuf, tid);
}

// ---------------------------------------------------------------------------
// Evolve. MODE 0: src = base (normalize inline, t==0 inits acc).
// MODE 1: src = prev partials (inline-reduce; t==0 folds pc[kprev] into acc).
// DO_FINAL: last-arriving block of each b computes out (jj loop covers DIM).
// ---------------------------------------------------------------------------
template<int MODE, bool DO_FINAL>
__global__ __launch_bounds__(512, 4) void evolve_kernel(
    const void* __restrict__ src, const float* __restrict__ uparams,
    const float* __restrict__ lcu, float2* __restrict__ pout,
    const float* __restrict__ pcoef, float2* __restrict__ acc, int kprev,
    int* __restrict__ cnt, float* __restrict__ out)
{
    __shared__ float4 exbuf[2048];
    __shared__ float red[9];
    __shared__ int sLast;

    const int b = blockIdx.x >> 3;
    const int t = blockIdx.x & 7;
    const int tid = threadIdx.x;
    const int lane = tid & 63;

    const float* __restrict__ th_row = uparams + (size_t)(b * NT + t) * NROT;
    float th0 = 0.5f * th_row[lane];
    float th1 = (lane < NROT - 64) ? 0.5f * th_row[64 + lane] : 0.f;
    float tc0 = cosf(th0), ts0 = sinf(th0);
    float tc1 = cosf(th1), ts1 = sinf(th1);

    float2 R[2], I[2];
    if constexpr (MODE == 0) {
        const float4* b4 = (const float4*)((const float*)src + (size_t)b * DIM);
        float4 v = b4[tid];
        float loc = v.x*v.x + v.y*v.y + v.z*v.z + v.w*v.w;
        for (int off = 32; off > 0; off >>= 1) loc += __shfl_down(loc, off, 64);
        if ((tid & 63) == 0) red[tid >> 6] = loc;
        __syncthreads();
        if (tid == 0) { float sm = 0.f; for (int w = 0; w < 8; ++w) sm += red[w]; red[8] = sm; }
        __syncthreads();
        const float inv = rsqrtf(red[8]);
        R[0] = make_float2(v.x * inv, v.y * inv);
        R[1] = make_float2(v.z * inv, v.w * inv);
        I[0] = make_float2(0.f, 0.f);
        I[1] = make_float2(0.f, 0.f);
        if (t == 0) {
            const float p0 = pcoef[0];
            float4* a4 = (float4*)(acc + (size_t)b * DIM);
            a4[tid*2+0] = make_float4(p0*R[0].x, 0.f, p0*R[0].y, 0.f);
            a4[tid*2+1] = make_float4(p0*R[1].x, 0.f, p0*R[1].y, 0.f);
        }
        __syncthreads();
    } else {
        R[0] = make_float2(0.f, 0.f); R[1] = make_float2(0.f, 0.f);
        I[0] = make_float2(0.f, 0.f); I[1] = make_float2(0.f, 0.f);
        const float2* s2 = (const float2*)src;
        for (int cc = 0; cc < NT; ++cc) {
            const float4* p4 = (const float4*)(s2 + ((size_t)b * NT + cc) * DIM);
#pragma unroll
            for (int m = 0; m < 2; ++m) {
                float4 v = p4[tid*2+m];
                R[m].x += v.x; I[m].x += v.y; R[m].y += v.z; I[m].y += v.w;
            }
        }
        if (t == 0 && kprev > 0) {
            const float pk = pcoef[kprev];
            float4* a4 = (float4*)(acc + (size_t)b * DIM);
#pragma unroll
            for (int m = 0; m < 2; ++m) {
                float4 v = a4[tid*2+m];
                v.x += pk * R[m].x; v.y += pk * I[m].x;
                v.z += pk * R[m].y; v.w += pk * I[m].y;
                a4[tid*2+m] = v;
            }
        }
    }

    evolve_once(R, I, tc0, ts0, tc1, ts1, exbuf, tid);

    const float coeff = lcu[b * NT + t];
    float4* o4 = (float4*)(pout + ((size_t)b * NT + t) * DIM);
#pragma unroll
    for (int m = 0; m < 2; ++m)
        o4[tid*2+m] = make_float4(coeff*R[m].x, coeff*I[m].x, coeff*R[m].y, coeff*I[m].y);

    if constexpr (DO_FINAL) {
        __threadfence();                  // publish this block's pout + acc writes
        __syncthreads();
        if (tid == 0) {
            int old = __hip_atomic_fetch_add(&cnt[b], 1, __ATOMIC_ACQ_REL,
                                             __HIP_MEMORY_SCOPE_AGENT);
            sLast = (old == NT - 1) ? 1 : 0;
        }
        __syncthreads();
        if (sLast) {
            __threadfence();              // acquire side: see all 8 blocks' writes
            float sabs = 0.f;
            for (int q = 0; q < NPC; ++q) sabs += fabsf(pcoef[q]);
            const float invn = 1.0f / sabs;
            const float pk = pcoef[NPC - 1];
            float4* outv = (float4*)(out + (size_t)b * DIM * 2);
            const float4* accv = (const float4*)(acc + (size_t)b * DIM);
#pragma unroll
            for (int jj = tid; jj < DIM / 2; jj += 512) {
                float4 sum = make_float4(0.f, 0.f, 0.f, 0.f);
                for (int cc = 0; cc < NT; ++cc) {
                    float4 v = ((const float4*)(pout + ((size_t)b * NT + cc) * DIM))[jj];
                    sum.x += v.x; sum.y += v.y; sum.z += v.z; sum.w += v.w;
                }
                float4 a = accv[jj];
                outv[jj] = make_float4((a.x + pk*sum.x) * invn, (a.y + pk*sum.y) * invn,
                                       (a.z + pk*sum.z) * invn, (a.w + pk*sum.w) * invn);
            }
        }
    }
}

extern "C" void kernel_launch(void* const* d_in, const int* in_sizes, int n_in,
                              void* d_out, int out_size, void* d_ws, size_t ws_size,
                              hipStream_t stream) {
    const float* base = (const float*)d_in[0];   // (64, 2048) f32
    const float* upar = (const float*)d_in[1];   // (64, 8, 88) f32
    const float* lcu  = (const float*)d_in[2];   // (64, 8) f32
    const float* pc   = (const float*)d_in[3];   // (4,) f32
    float* out = (float*)d_out;                  // (64, 2048, 2) f32

    const size_t plane = (size_t)BSZ * DIM * sizeof(float2);   // 1 MB
    const size_t cnt_bytes = (size_t)BSZ * sizeof(int);
    char* ws = (char*)d_ws;

    float2* acc = (float2*)ws;
    float2* pA  = (float2*)(ws + plane);
    float2* pB  = (float2*)(ws + plane + (size_t)NT * plane);
    float2* pC  = (float2*)(ws + plane + (size_t)2 * NT * plane);
    int* cnt    = (int*)(ws + plane + (size_t)3 * NT * plane);

    if (ws_size >= (1 + 3 * (size_t)NT) * plane + cnt_bytes) {
        hipMemsetAsync(cnt, 0, cnt_bytes, stream);
        evolve_kernel<0, false><<<BSZ * NT, 512, 0, stream>>>(
            base, upar, lcu, pA, pc, acc, 0, nullptr, nullptr);
        evolve_kernel<1, false><<<BSZ * NT, 512, 0, stream>>>(
            pA, upar, lcu, pB, pc, acc, 1, nullptr, nullptr);
        evolve_kernel<1, true><<<BSZ * NT, 512, 0, stream>>>(
            pB, upar, lcu, pC, pc, acc, 2, cnt, out);
    } else {
        // compact fallback: alternate pA/pB (needs 1+2*NT MB + cnt)
        float2* qA = (float2*)(ws + plane);
        float2* qB = (float2*)(ws + plane + (size_t)NT * plane);
        int* c2    = (int*)(ws + plane + (size_t)2 * NT * plane);
        hipMemsetAsync(c2, 0, cnt_bytes, stream);
        evolve_kernel<0, false><<<BSZ * NT, 512, 0, stream>>>(
            base, upar, lcu, qA, pc, acc, 0, nullptr, nullptr);
        evolve_kernel<1, false><<<BSZ * NT, 512, 0, stream>>>(
            qA, upar, lcu, qB, pc, acc, 1, nullptr, nullptr);
        evolve_kernel<1, true><<<BSZ * NT, 512, 0, stream>>>(
            qB, upar, lcu, qA, pc, acc, 2, c2, out);
    }
}

// Round 17
// 84.764 us; speedup vs baseline: 4.4340x; 2.8945x over previous
//
#include <hip/hip_runtime.h>
#include <utility>

#define DIM 2048
#define NQ 11
#define NROT 88
#define BSZ 64
#define NT 8
#define NPC 4   // DEGREE+1

#if __has_builtin(__builtin_amdgcn_permlane16_swap)
#define HAVE_PL16 1
#else
#define HAVE_PL16 0
#endif
#if __has_builtin(__builtin_amdgcn_permlane32_swap)
#define HAVE_PL32 1
#else
#define HAVE_PL32 0
#endif

// ---------------------------------------------------------------------------
// Compile-time gate schedule. Gate G in [0,88); wire w <-> state bit 10-w.
// ---------------------------------------------------------------------------
constexpr int g_type(int G) {
    int j = G % 44;
    return (j < 11 || (j >= 22 && j < 33)) ? 0 : 1;   // 0=RY, 1=CRX
}
constexpr int g_pt(int G) {
    int j = G % 44;
    if (j < 11) return 10 - j;
    if (j < 22) { int i = 21 - j; int tw = (i + 1 == NQ) ? 0 : i + 1; return 10 - tw; }
    if (j < 33) return 10 - (j - 22);
    if (j == 33) return 1;
    int i = j - 34; int tw = (i + 10) % NQ; return 10 - tw;
}
constexpr int g_pcb(int G) {
    int j = G % 44;
    if (j >= 11 && j < 22) { int i = 21 - j; return 10 - i; }
    if (j == 33) return 0;
    if (j >= 34) { int i = j - 34; return 10 - i; }
    return -1;  // RY
}
constexpr bool use_sum_tier(int lb) {
    return (lb == 4 && HAVE_PL16) || (lb == 5 && HAVE_PL32);
}

// Transposed-layout bit map: swap state bits 2<->8, 3<->9, 5<->10 (r9-proven).
constexpr int tmap(int b) {
    if (b == 2) return 8;  if (b == 8) return 2;
    if (b == 3) return 9;  if (b == 9) return 3;
    if (b == 5) return 10; if (b == 10) return 5;
    return b;
}

// ---------------------------------------------------------------------------
// Per-layer op schedule (48 ops: 44 gates + 4 transposes), r9-proven.
// ---------------------------------------------------------------------------
constexpr int lop_j(int k) {
    if (k < 8)  return 3 + k;
    if (k == 8) return -1;
    if (k < 12) return k - 9;
    if (k == 12) return 11;
    if (k == 13) return -1;
    if (k < 22) return 12 + (k - 14);
    if (k == 22) return -1;
    if (k == 23) return 20;
    if (k == 24) return 21;
    if (k < 31) { int w[6] = {0, 1, 2, 3, 9, 10}; return 22 + w[k - 25]; }
    if (k < 36) return 33 + (k - 31);
    if (k == 36) return -1;
    if (k < 42) return 26 + (k - 37);
    return 38 + (k - 42);
}
constexpr bool lop_B(int k) {
    return (k >= 9 && k <= 12) || (k >= 23 && k <= 35);
}
constexpr int lop_tpar(int k) { return (k == 8 || k == 22) ? 0 : 1; }

// ---------------------------------------------------------------------------
// Wave-uniform trig fetch via readlane.
// ---------------------------------------------------------------------------
template<int G>
__device__ __forceinline__ void get_cs(float c0, float s0, float c1, float s1,
                                       float& c, float& s) {
    if constexpr (G < 64) {
        c = __int_as_float(__builtin_amdgcn_readlane(__float_as_int(c0), G));
        s = __int_as_float(__builtin_amdgcn_readlane(__float_as_int(s0), G));
    } else {
        c = __int_as_float(__builtin_amdgcn_readlane(__float_as_int(c1), G - 64));
        s = __int_as_float(__builtin_amdgcn_readlane(__float_as_int(s1), G - 64));
    }
}

// ---------------------------------------------------------------------------
// Lane exchange across tid bit LB (state bit LB+2) — PARTNER form.
// ---------------------------------------------------------------------------
template<int LB>
__device__ __forceinline__ float lxp(float x) {
    if constexpr (LB == 0) {
        return __int_as_float(__builtin_amdgcn_update_dpp(
            __float_as_int(x), __float_as_int(x), 0xB1, 0xF, 0xF, true)); // xor1
    } else if constexpr (LB == 1) {
        return __int_as_float(__builtin_amdgcn_update_dpp(
            __float_as_int(x), __float_as_int(x), 0x4E, 0xF, 0xF, true)); // xor2
    } else if constexpr (LB == 2) {
        return __int_as_float(__builtin_amdgcn_ds_swizzle(__float_as_int(x), 0x101F)); // xor4
    } else if constexpr (LB == 3) {
        return __int_as_float(__builtin_amdgcn_update_dpp(
            __float_as_int(x), __float_as_int(x), 0x128, 0xF, 0xF, true)); // row_ror:8 = xor8
    } else if constexpr (LB == 4) {
        return __int_as_float(__builtin_amdgcn_ds_swizzle(__float_as_int(x), 0x401F)); // xor16
    } else {
        return __shfl_xor(x, 32, 64);                                                  // xor32
    }
}

// SUM form: returns own + partner (order-immune to permlane*_swap ordering).
template<int LB>
__device__ __forceinline__ float lxsum(float x) {
#if HAVE_PL16
    if constexpr (LB == 4) {
        unsigned u = __float_as_uint(x);
        auto r = __builtin_amdgcn_permlane16_swap(u, u, false, false);
        return __uint_as_float(r[0]) + __uint_as_float(r[1]);
    }
#endif
#if HAVE_PL32
    if constexpr (LB == 5) {
        unsigned u = __float_as_uint(x);
        auto r = __builtin_amdgcn_permlane32_swap(u, u, false, false);
        return __uint_as_float(r[0]) + __uint_as_float(r[1]);
    }
#endif
    return x + lxp<LB>(x);
}

// ---------------------------------------------------------------------------
// Layout: 512 threads, thread tid holds amps a = tid*4 + (2m+e), m,e in {0,1}.
//   amp bits: 0=e, 1=m, 2..7=lane(tid 0..5), 8..10=block(tid 6..8)
// Layout B via transpose: bits (2,3,5) <-> (8,9,10).  [r9-proven, 85.2us]
// ---------------------------------------------------------------------------
template<int G, bool PB>
__device__ __forceinline__ void apply_gate(
    float2 (&R)[2], float2 (&I)[2],
    float c0, float s0, float c1, float s1, const int tid)
{
    constexpr int type = g_type(G);
    constexpr int pt   = PB ? tmap(g_pt(G)) : g_pt(G);
    constexpr int pcb0 = g_pcb(G);
    constexpr int pcb  = (pcb0 < 0) ? -1 : (PB ? tmap(pcb0) : pcb0);
    static_assert(pt <= 7, "block-bit target must run in transposed layout");
    float c, s;
    get_cs<G>(c0, s0, c1, s1, c, s);

    if constexpr (pt == 0) {
        if constexpr (type == 0) {
#pragma unroll
            for (int m = 0; m < 2; ++m) {
                float er = R[m].x, orr = R[m].y, ei = I[m].x, oi = I[m].y;
                R[m].x = c*er - s*orr;  R[m].y = s*er + c*orr;
                I[m].x = c*ei - s*oi;   I[m].y = s*ei + c*oi;
            }
        } else if constexpr (pcb == 1) {
            float er = R[1].x, orr = R[1].y, ei = I[1].x, oi = I[1].y;
            R[1].x = c*er + s*oi;   I[1].x = c*ei - s*orr;
            R[1].y = c*orr + s*ei;  I[1].y = c*oi - s*er;
        } else {
            const bool ctrl = (tid >> (pcb - 2)) & 1;
            if (ctrl) {
#pragma unroll
                for (int m = 0; m < 2; ++m) {
                    float er = R[m].x, orr = R[m].y, ei = I[m].x, oi = I[m].y;
                    R[m].x = c*er + s*oi;   I[m].x = c*ei - s*orr;
                    R[m].y = c*orr + s*ei;  I[m].y = c*oi - s*er;
                }
            }
        }
    } else if constexpr (pt == 1) {
        if constexpr (type == 0) {
            float2 l = R[0], h = R[1], li = I[0], hi = I[1];
            R[0].x = c*l.x - s*h.x;   R[0].y = c*l.y - s*h.y;
            R[1].x = s*l.x + c*h.x;   R[1].y = s*l.y + c*h.y;
            I[0].x = c*li.x - s*hi.x; I[0].y = c*li.y - s*hi.y;
            I[1].x = s*li.x + c*hi.x; I[1].y = s*li.y + c*hi.y;
        } else if constexpr (pcb == 0) {
            float lr = R[0].y, li = I[0].y, hr = R[1].y, hi = I[1].y;
            R[0].y = c*lr + s*hi;   I[0].y = c*li - s*hr;
            R[1].y = c*hr + s*li;   I[1].y = c*hi - s*lr;
        } else {
            const bool ctrl = (tid >> (pcb - 2)) & 1;
            if (ctrl) {
                float2 l = R[0], h = R[1], li = I[0], hi = I[1];
                R[0].x = c*l.x + s*hi.x;  R[0].y = c*l.y + s*hi.y;
                I[0].x = c*li.x - s*h.x;  I[0].y = c*li.y - s*h.y;
                R[1].x = c*h.x + s*li.x;  R[1].y = c*h.y + s*li.y;
                I[1].x = c*hi.x - s*l.x;  I[1].y = c*hi.y - s*l.y;
            }
        }
    } else {
        constexpr int lb = pt - 2;
        if constexpr (use_sum_tier(lb)) {
            if constexpr (type == 0) {
                const float sg = ((tid >> lb) & 1) ? s : -s;
                const float k1 = c - sg;
#pragma unroll
                for (int m = 0; m < 2; ++m) {
                    float srx = lxsum<lb>(R[m].x), sry = lxsum<lb>(R[m].y);
                    float six = lxsum<lb>(I[m].x), siy = lxsum<lb>(I[m].y);
                    R[m].x = k1*R[m].x + sg*srx;  R[m].y = k1*R[m].y + sg*sry;
                    I[m].x = k1*I[m].x + sg*six;  I[m].y = k1*I[m].y + sg*siy;
                }
            } else if constexpr (pcb == 0) {
#pragma unroll
                for (int m = 0; m < 2; ++m) {
                    float sR = lxsum<lb>(R[m].y), sI = lxsum<lb>(I[m].y);
                    float r = R[m].y, i = I[m].y;
                    R[m].y = c*r - s*i + s*sI;
                    I[m].y = c*i + s*r - s*sR;
                }
            } else if constexpr (pcb == 1) {
                float sRx = lxsum<lb>(R[1].x), sRy = lxsum<lb>(R[1].y);
                float sIx = lxsum<lb>(I[1].x), sIy = lxsum<lb>(I[1].y);
                float rx = R[1].x, ry = R[1].y, ix = I[1].x, iy = I[1].y;
                R[1].x = c*rx - s*ix + s*sIx;  R[1].y = c*ry - s*iy + s*sIy;
                I[1].x = c*ix + s*rx - s*sRx;  I[1].y = c*iy + s*ry - s*sRy;
            } else {
                const bool ctrl = (tid >> (pcb - 2)) & 1;
                if (ctrl) {
#pragma unroll
                    for (int m = 0; m < 2; ++m) {
                        float sRx = lxsum<lb>(R[m].x), sRy = lxsum<lb>(R[m].y);
                        float sIx = lxsum<lb>(I[m].x), sIy = lxsum<lb>(I[m].y);
                        float rx = R[m].x, ry = R[m].y, ix = I[m].x, iy = I[m].y;
                        R[m].x = c*rx - s*ix + s*sIx;  R[m].y = c*ry - s*iy + s*sIy;
                        I[m].x = c*ix + s*rx - s*sRx;  I[m].y = c*iy + s*ry - s*sRy;
                    }
                }
            }
        } else {
            if constexpr (type == 0) {
                const float sg = ((tid >> lb) & 1) ? s : -s;
#pragma unroll
                for (int m = 0; m < 2; ++m) {
                    float prx = lxp<lb>(R[m].x), pry = lxp<lb>(R[m].y);
                    float pix = lxp<lb>(I[m].x), piy = lxp<lb>(I[m].y);
                    R[m].x = c*R[m].x + sg*prx;  R[m].y = c*R[m].y + sg*pry;
                    I[m].x = c*I[m].x + sg*pix;  I[m].y = c*I[m].y + sg*piy;
                }
            } else if constexpr (pcb == 0) {
#pragma unroll
                for (int m = 0; m < 2; ++m) {
                    float pry = lxp<lb>(R[m].y), piy = lxp<lb>(I[m].y);
                    R[m].y = c*R[m].y + s*piy;
                    I[m].y = c*I[m].y - s*pry;
                }
            } else if constexpr (pcb == 1) {
                float prx = lxp<lb>(R[1].x), pry = lxp<lb>(R[1].y);
                float pix = lxp<lb>(I[1].x), piy = lxp<lb>(I[1].y);
                R[1].x = c*R[1].x + s*pix;  R[1].y = c*R[1].y + s*piy;
                I[1].x = c*I[1].x - s*prx;  I[1].y = c*I[1].y - s*pry;
            } else {
                const bool ctrl = (tid >> (pcb - 2)) & 1;
                if (ctrl) {
#pragma unroll
                    for (int m = 0; m < 2; ++m) {
                        float prx = lxp<lb>(R[m].x), pry = lxp<lb>(R[m].y);
                        float pix = lxp<lb>(I[m].x), piy = lxp<lb>(I[m].y);
                        R[m].x = c*R[m].x + s*pix;  R[m].y = c*R[m].y + s*piy;
                        I[m].x = c*I[m].x - s*prx;  I[m].y = c*I[m].y - s*pry;
                    }
                }
            }
        }
    }
}

// ---------------------------------------------------------------------------
// Whole-payload thread transpose: swap tid bits (0,1,3) <-> (6,7,8) via LDS.
// ---------------------------------------------------------------------------
__device__ __forceinline__ int swz(int s) { return s ^ ((s >> 7) & 7); }

template<int PAR>
__device__ __forceinline__ void transpose_swap(float2 (&R)[2], float2 (&I)[2],
                                               float4* __restrict__ exbuf, const int tid)
{
    float4* buf = exbuf + PAR * 1024;
    const int d06 = ((tid >> 0) ^ (tid >> 6)) & 1;
    const int d17 = ((tid >> 1) ^ (tid >> 7)) & 1;
    const int d38 = ((tid >> 3) ^ (tid >> 8)) & 1;
    const int q = tid ^ (d06 * 65) ^ (d17 * 130) ^ (d38 * 264);
    buf[swz(tid * 2 + 0)] = make_float4(R[0].x, R[0].y, I[0].x, I[0].y);
    buf[swz(tid * 2 + 1)] = make_float4(R[1].x, R[1].y, I[1].x, I[1].y);
    __syncthreads();
    float4 v0 = buf[swz(q * 2 + 0)];
    float4 v1 = buf[swz(q * 2 + 1)];
    R[0] = make_float2(v0.x, v0.y); I[0] = make_float2(v0.z, v0.w);
    R[1] = make_float2(v1.x, v1.y); I[1] = make_float2(v1.z, v1.w);
    // no trailing barrier: parity buffer reused 2 transposes later; the
    // intervening transpose's barrier orders those reads before writes.
}

// ---------------------------------------------------------------------------
// Op dispatcher over the 96-op schedule (2 layers x 48).
// ---------------------------------------------------------------------------
template<int K>
__device__ __forceinline__ void apply_op(
    float2 (&R)[2], float2 (&I)[2],
    float c0, float s0, float c1, float s1,
    float4* __restrict__ exbuf, const int tid)
{
    constexpr int layer = K / 48;
    constexpr int k = K % 48;
    constexpr int j = lop_j(k);
    if constexpr (j < 0) {
        transpose_swap<lop_tpar(k)>(R, I, exbuf, tid);
    } else {
        apply_gate<layer * 44 + j, lop_B(k)>(R, I, c0, s0, c1, s1, tid);
    }
}

template<int... Ks>
__device__ __forceinline__ void apply_all(std::integer_sequence<int, Ks...>,
    float2 (&R)[2], float2 (&I)[2],
    float c0, float s0, float c1, float s1,
    float4* __restrict__ exbuf, const int tid)
{
    (apply_op<Ks>(R, I, c0, s0, c1, s1, exbuf, tid), ...);
}

// ---------------------------------------------------------------------------
// Evolve. MODE 0: src = base (f32 real), normalize inline, t==0 writes
// acc = pc0*base. MODE 1: src = prev partials, inline-reduce; t==0 folds
// pc[kprev]*working into acc. MODE 2: src = working (fallback path).
// ---------------------------------------------------------------------------
template<int MODE>
__global__ __launch_bounds__(512, 4) void evolve_kernel(
    const void* __restrict__ src, const float* __restrict__ uparams,
    const float* __restrict__ lcu, float2* __restrict__ pout,
    const float* __restrict__ pcoef, float2* __restrict__ acc, int kprev)
{
    __shared__ float4 exbuf[2048];          // 2 x 1024 float4 (dbuf) = 32 KB
    __shared__ float red[9];

    const int b = blockIdx.x >> 3;
    const int t = blockIdx.x & 7;
    const int tid = threadIdx.x;
    const int lane = tid & 63;

    const float* __restrict__ th_row = uparams + (size_t)(b * NT + t) * NROT;
    float th0 = 0.5f * th_row[lane];
    float th1 = (lane < NROT - 64) ? 0.5f * th_row[64 + lane] : 0.f;
    float tc0 = cosf(th0), ts0 = sinf(th0);
    float tc1 = cosf(th1), ts1 = sinf(th1);

    float2 R[2], I[2];
    if constexpr (MODE == 0) {
        const float4* b4 = (const float4*)((const float*)src + (size_t)b * DIM);
        float4 v = b4[tid];
        float loc = v.x*v.x + v.y*v.y + v.z*v.z + v.w*v.w;
        for (int off = 32; off > 0; off >>= 1) loc += __shfl_down(loc, off, 64);
        if ((tid & 63) == 0) red[tid >> 6] = loc;
        __syncthreads();
        if (tid == 0) { float sm = 0.f; for (int w = 0; w < 8; ++w) sm += red[w]; red[8] = sm; }
        __syncthreads();
        const float inv = rsqrtf(red[8]);
        R[0] = make_float2(v.x * inv, v.y * inv);
        R[1] = make_float2(v.z * inv, v.w * inv);
        I[0] = make_float2(0.f, 0.f);
        I[1] = make_float2(0.f, 0.f);
        if (t == 0) {
            const float p0 = pcoef[0];
            float4* a4 = (float4*)(acc + (size_t)b * DIM);
            a4[tid*2+0] = make_float4(p0*R[0].x, 0.f, p0*R[0].y, 0.f);
            a4[tid*2+1] = make_float4(p0*R[1].x, 0.f, p0*R[1].y, 0.f);
        }
        __syncthreads();
    } else {
        R[0] = make_float2(0.f, 0.f); R[1] = make_float2(0.f, 0.f);
        I[0] = make_float2(0.f, 0.f); I[1] = make_float2(0.f, 0.f);
        const float2* s2 = (const float2*)src;
        for (int cc = 0; cc < NT; ++cc) {
            const float4* p4 = (const float4*)(s2 + ((size_t)b * NT + cc) * DIM);
#pragma unroll
            for (int m = 0; m < 2; ++m) {
                float4 v = p4[tid*2+m];
                R[m].x += v.x; I[m].x += v.y; R[m].y += v.z; I[m].y += v.w;
            }
        }
        if (t == 0 && kprev > 0) {
            const float pk = pcoef[kprev];
            float4* a4 = (float4*)(acc + (size_t)b * DIM);
#pragma unroll
            for (int m = 0; m < 2; ++m) {
                float4 v = a4[tid*2+m];
                v.x += pk * R[m].x; v.y += pk * I[m].x;
                v.z += pk * R[m].y; v.w += pk * I[m].y;
                a4[tid*2+m] = v;
            }
        }
    }

    apply_all(std::make_integer_sequence<int, 96>{}, R, I,
              tc0, ts0, tc1, ts1, exbuf, tid);

    const float coeff = lcu[b * NT + t];
    float4* o4 = (float4*)(pout + ((size_t)b * NT + t) * DIM);
#pragma unroll
    for (int m = 0; m < 2; ++m)
        o4[tid*2+m] = make_float4(coeff*R[m].x, coeff*I[m].x, coeff*R[m].y, coeff*I[m].y);
}

// ---------------------------------------------------------------------------
// Final: out = (acc + pc[NPC-1] * rowsum(partial_last)) / sum|pc|
// ---------------------------------------------------------------------------
__global__ __launch_bounds__(256) void final_kernel(
    const float2* __restrict__ partial, const float* __restrict__ pcoef,
    const float2* __restrict__ acc, float* __restrict__ out)
{
    int b = blockIdx.x >> 3;
    int i = ((blockIdx.x & 7) << 8) | threadIdx.x;
    float sr = 0.f, si = 0.f;
    for (int c = 0; c < NT; ++c) {
        float2 v = partial[((size_t)b * NT + c) * DIM + i];
        sr += v.x; si += v.y;
    }
    float sabs = 0.f;
    for (int q = 0; q < NPC; ++q) sabs += fabsf(pcoef[q]);
    float invn = 1.0f / sabs;
    float pk = pcoef[NPC - 1];
    float2 a = acc[(size_t)b * DIM + i];
    out[((size_t)b * DIM + i) * 2 + 0] = (a.x + pk * sr) * invn;
    out[((size_t)b * DIM + i) * 2 + 1] = (a.y + pk * si) * invn;
}

extern "C" void kernel_launch(void* const* d_in, const int* in_sizes, int n_in,
                              void* d_out, int out_size, void* d_ws, size_t ws_size,
                              hipStream_t stream) {
    const float* base = (const float*)d_in[0];   // (64, 2048) f32
    const float* upar = (const float*)d_in[1];   // (64, 8, 88) f32
    const float* lcu  = (const float*)d_in[2];   // (64, 8) f32
    const float* pc   = (const float*)d_in[3];   // (4,) f32
    float* out = (float*)d_out;                  // (64, 2048, 2) f32

    const size_t plane = (size_t)BSZ * DIM * sizeof(float2);   // 1 MB
    char* ws = (char*)d_ws;

    if (ws_size >= (1 + 3 * (size_t)NT) * plane) {
        // r9-proven 4-launch path (85.2 us)
        float2* acc = (float2*)ws;
        float2* pA  = (float2*)(ws + plane);
        float2* pB  = (float2*)(ws + plane + (size_t)NT * plane);
        float2* pC  = (float2*)(ws + plane + (size_t)2 * NT * plane);
        evolve_kernel<0><<<BSZ * NT, 512, 0, stream>>>(base, upar, lcu, pA, pc, acc, 0);
        evolve_kernel<1><<<BSZ * NT, 512, 0, stream>>>(pA,   upar, lcu, pB, pc, acc, 1);
        evolve_kernel<1><<<BSZ * NT, 512, 0, stream>>>(pB,   upar, lcu, pC, pc, acc, 2);
        final_kernel<<<BSZ * 8, 256, 0, stream>>>(pC, pc, acc, out);
    } else {
        // compact fallback: ping-pong pA/pB (needs 1+2*NT MB)
        float2* acc = (float2*)ws;
        float2* pA  = (float2*)(ws + plane);
        float2* pB  = (float2*)(ws + plane + (size_t)NT * plane);
        evolve_kernel<0><<<BSZ * NT, 512, 0, stream>>>(base, upar, lcu, pA, pc, acc, 0);
        evolve_kernel<1><<<BSZ * NT, 512, 0, stream>>>(pA,   upar, lcu, pB, pc, acc, 1);
        evolve_kernel<1><<<BSZ * NT, 512, 0, stream>>>(pB,   upar, lcu, pA, pc, acc, 2);
        final_kernel<<<BSZ * 8, 256, 0, stream>>>(pA, pc, acc, out);
    }
}